// Round 1
// 395.100 us; speedup vs baseline: 1.0067x; 1.0067x over previous
//
#include <hip/hip_runtime.h>
#include <hip/hip_bf16.h>

typedef unsigned short u16;
typedef __attribute__((ext_vector_type(8))) short short8;
typedef __attribute__((ext_vector_type(4))) float f32x4;
typedef __attribute__((ext_vector_type(16))) float f32x16;
typedef __attribute__((ext_vector_type(2))) __bf16 bf16x2;

#define NNODES 100000
#define NEDGES 600000
#define NGRAPHS 512
#define HF 128
#define EF 256
#define GB 32       // graphs per head block

// chunk-major LDS planes, 32-node tiles: plane = 32 rows x 16B + 16B pad
// -> stride 264 u16 (528 B = 132 dwords == 4 banks mod 32)
#define PLD 264
__device__ __forceinline__ int cidx(int chunk, int row){ return chunk * PLD + row * 8; }

__device__ __forceinline__ float bfu(u16 u){ return __uint_as_float(((unsigned)u) << 16); }
__device__ __forceinline__ u16 f2bf(float f){
    unsigned u = __float_as_uint(f);
    unsigned r = (u + 0x7fff + ((u >> 16) & 1)) >> 16;
    return (u16)r;
}
// HW packed f32->bf16 RNE (v_cvt_pk_bf16_f32 on gfx950)
__device__ __forceinline__ unsigned pack2(float a, float b){
    bf16x2 v = { (__bf16)a, (__bf16)b };
    return __builtin_bit_cast(unsigned, v);
}

#if __has_builtin(__builtin_amdgcn_rcpf)
#define RCP1(x) __builtin_amdgcn_rcpf(x)
#else
#define RCP1(x) (1.f / (x))
#endif

// cheap softplus: log(1+exp(x)) direct — safe for |x| << 80 (values here <~20)
__device__ __forceinline__ float sp_f(float x){
    return __logf(1.f + __expf(x));
}
__device__ __forceinline__ float sig_f(float x){
    return RCP1(1.f + __expf(-x));
}
__device__ __forceinline__ float lf(const void* p, long i, bool f32){
    return f32 ? ((const float*)p)[i] : bfu(((const u16*)p)[i]);
}

// in-register dtype detection: probe 256 u16 of the embed table as bf16
__device__ __forceinline__ bool is_f32(const void* probe){
    const u16* p = (const u16*)probe;
    int lane = threadIdx.x & 63;
    int c = 0;
#pragma unroll
    for (int i = 0; i < 4; i++) c += (fabsf(bfu(p[lane * 4 + i])) > 1.0f) ? 1 : 0;
#pragma unroll
    for (int off = 32; off; off >>= 1) c += __shfl_xor(c, off, 64);
    return c > 8;
}

// ---------------- prep: weight repack + edge count + xsum zero ----------------
// conv weights -> 32x32x16 A-frag order: P[ks][nt32][lane][8]; lane l holds
//   W[k = ks*16 + (l>>5)*8 + j][n = nt32*32 + (l&31)], j=0..7  (W^T as A operand)
// head weights -> 16x16x32 frag order.
// blocks [0,960): conv; [960,1152): head; [1152,3496): edge count;
// [3496,3560): zero xsum (64 blocks x 256 x float4)
__global__ __launch_bounds__(256) void prep_kernel(const void* __restrict__ wg,
                                                   const void* __restrict__ we1,
                                                   const void* __restrict__ we2,
                                                   const void* __restrict__ wp,
                                                   const void* __restrict__ wfc1,
                                                   const void* __restrict__ wfc2,
                                                   u16* __restrict__ pwg,
                                                   u16* __restrict__ pwe1,
                                                   u16* __restrict__ pwe2,
                                                   u16* __restrict__ pwp,
                                                   u16* __restrict__ pf1,
                                                   u16* __restrict__ pf2,
                                                   const void* __restrict__ emb,
                                                   const int* __restrict__ tgt,
                                                   int* __restrict__ counts,
                                                   float* __restrict__ xsum){
    int b = blockIdx.x, t = threadIdx.x;
    if (b < 960) {
        bool f32 = is_f32(emb);
        int i = b * 256 + t;                       // < 3*81920
        int c = i / 81920, r = i % 81920;
        const void* src; u16* dst; int N, KN, l;
        if (r < 16384)      { src = wg;  dst = pwg;  N = HF; KN = 16384; l = r; }
        else if (r < 49152) { src = we1; dst = pwe1; N = EF; KN = 32768; l = r - 16384; }
        else                { src = we2; dst = pwe2; N = HF; KN = 32768; l = r - 49152; }
        int j = l & 7, lane = (l >> 3) & 63, rest = l >> 9;
        int NT = N >> 5;
        int nt = rest % NT, ks = rest / NT;
        int k = ks * 16 + (lane >> 5) * 8 + j;
        int n = nt * 32 + (lane & 31);
        long base = (long)c * KN;
        dst[base + l] = f2bf(lf(src, base + (long)k * N + n, f32));
    } else if (b < 1152) {
        bool f32 = is_f32(emb);
        int i = (b - 960) * 256 + t;               // < 3*16384
        int c = i / 16384, l = i % 16384;
        const void* src = (c == 0) ? wp : (c == 1) ? wfc1 : wfc2;
        u16* dst = (c == 0) ? pwp : (c == 1) ? pf1 : pf2;
        int j = l & 7, lane = (l >> 3) & 63, rest = l >> 9;
        int nt = rest & 7, kt = rest >> 3;         // 16x16 layout, N=128
        int k = kt * 32 + (lane >> 4) * 8 + j;
        int n = nt * 16 + (lane & 15);
        dst[l] = f2bf(lf(src, (long)k * HF + n, f32));
    } else if (b < 3496) {
        int e = (b - 1152) * 256 + t;
        if (e < NEDGES) atomicAdd(&counts[tgt[e]], 1);
    } else {
        int i = (b - 3496) * 256 + t;              // < 16384 float4s
        ((float4*)xsum)[i] = make_float4(0.f, 0.f, 0.f, 0.f);
    }
}

// ---------------- CSR build ----------------
__global__ __launch_bounds__(256) void scan1_kernel(const int* __restrict__ counts,
                                                    int* __restrict__ row_ptr,
                                                    int* __restrict__ bsums){
    __shared__ int s[256];
    int t = threadIdx.x;
    int i = blockIdx.x * 256 + t;
    int v = (i < NNODES) ? counts[i] : 0;
    s[t] = v; __syncthreads();
    for (int off = 1; off < 256; off <<= 1) {
        int a = (t >= off) ? s[t - off] : 0;
        __syncthreads();
        s[t] += a;
        __syncthreads();
    }
    if (i < NNODES) row_ptr[i] = s[t] - v;
    if (t == 255) bsums[blockIdx.x] = s[255];
}

__global__ __launch_bounds__(512) void scan2_kernel(const int* __restrict__ bsums,
                                                    int* __restrict__ boffs, int nb){
    __shared__ int s[512];
    int t = threadIdx.x;
    int v = (t < nb) ? bsums[t] : 0;
    s[t] = v; __syncthreads();
    for (int off = 1; off < 512; off <<= 1) {
        int a = (t >= off) ? s[t - off] : 0;
        __syncthreads();
        s[t] += a;
        __syncthreads();
    }
    if (t < nb) boffs[t] = s[t] - v;
}

__global__ __launch_bounds__(256) void scan3_kernel(int* __restrict__ row_ptr,
                                                    const int* __restrict__ boffs,
                                                    int* __restrict__ cursor){
    int i = blockIdx.x * 256 + threadIdx.x;
    if (i < NNODES) {
        int r = row_ptr[i] + boffs[blockIdx.x];
        row_ptr[i] = r;
        cursor[i]  = r;
    }
}

__global__ __launch_bounds__(256) void fill_kernel(const int* __restrict__ src,
                                                   const int* __restrict__ tgt,
                                                   int* __restrict__ cursor,
                                                   int* __restrict__ es){
    int e = blockIdx.x * 256 + threadIdx.x;
    if (e < NEDGES) {
        int pos = atomicAdd(&cursor[tgt[e]], 1);
        es[pos] = src[e];
    }
}

// ========== conv MFMA phases, 32x32x16, TWO 32-node tiles per block ==========
// Every A-fragment load (We1/We2/Wg) is reused for both node sub-tiles:
// per-block weight L2 traffic unchanged (160 KB) but now covers 64 nodes,
// halving total conv weight streaming (500 MB -> 250 MB per conv).
// LDS 4 x 8.45 KB = 33.8 KB -> 4 blocks/CU (16 waves/CU).
// Register discipline: A[8] preloaded once per pass; sub-tiles' U computed
// sequentially reusing one acc; only aTA/aTB (32 f32) persist across passes.
// K-step accumulation order per tile is identical to the 1-tile version
// (bit-exact numerics per node).
__device__ __forceinline__ void conv_phases2(u16* xsA, u16* xsB, u16* usA, u16* usB,
                                             const u16* __restrict__ pwg,
                                             const u16* __restrict__ pwe1,
                                             const u16* __restrict__ pwe2,
                                             u16* __restrict__ M, long row0){
    const int t = threadIdx.x;
    const int w = t >> 6, lane = t & 63;
    const int half = lane >> 5, nn = lane & 31;

    f32x16 aTA = {}, aTB = {};
#pragma unroll
    for (int p = 0; p < 2; p++) {
        // ---- U half-pass: wave w owns ef-tile et = p*4 + w ----
        int et = p * 4 + w;
        short8 A[8];
#pragma unroll
        for (int ks = 0; ks < 8; ks++)
            A[ks] = *(const short8*)(pwe1 + (((ks * 8 + et) * 64 + lane) << 3));
        {   // sub-tile A
            f32x16 acc = {};
#pragma unroll
            for (int ks = 0; ks < 8; ks++) {
                short8 B = *(const short8*)(&xsA[cidx(ks * 2 + half, nn)]);
                acc = __builtin_amdgcn_mfma_f32_32x32x16_bf16(A[ks], B, acc, 0, 0, 0);
            }
#pragma unroll
            for (int q = 0; q < 4; q++) {
                uint2 d;
                d.x = pack2(sp_f(acc[q*4+0]), sp_f(acc[q*4+1]));
                d.y = pack2(sp_f(acc[q*4+2]), sp_f(acc[q*4+3]));
                *(uint2*)(&usA[cidx(w * 4 + q, nn) + half * 4]) = d;
            }
        }
        {   // sub-tile B (reuses A[ks] — no extra weight loads)
            f32x16 acc = {};
#pragma unroll
            for (int ks = 0; ks < 8; ks++) {
                short8 B = *(const short8*)(&xsB[cidx(ks * 2 + half, nn)]);
                acc = __builtin_amdgcn_mfma_f32_32x32x16_bf16(A[ks], B, acc, 0, 0, 0);
            }
#pragma unroll
            for (int q = 0; q < 4; q++) {
                uint2 d;
                d.x = pack2(sp_f(acc[q*4+0]), sp_f(acc[q*4+1]));
                d.y = pack2(sp_f(acc[q*4+2]), sp_f(acc[q*4+3]));
                *(uint2*)(&usB[cidx(w * 4 + q, nn) + half * 4]) = d;
            }
        }
        __syncthreads();
        // ---- C partial: aT += We2^T[h-tile w][K-half p] @ U-half (both tiles) ----
#pragma unroll
        for (int j = 0; j < 8; j++) {
            short8 Ac = *(const short8*)(pwe2 + ((((p * 8 + j) * 4 + w) * 64 + lane) << 3));
            short8 BA = *(const short8*)(&usA[cidx(j * 2 + half, nn)]);
            aTA = __builtin_amdgcn_mfma_f32_32x32x16_bf16(Ac, BA, aTA, 0, 0, 0);
            short8 BB = *(const short8*)(&usB[cidx(j * 2 + half, nn)]);
            aTB = __builtin_amdgcn_mfma_f32_32x32x16_bf16(Ac, BB, aTB, 0, 0, 0);
        }
        if (p == 0) __syncthreads();               // usA/usB reused by pass 1
    }

    // ---- G phase: aG = Wg^T[h-tile w] @ x^T; fused gate+write per tile ----
    short8 Ag[8];
#pragma unroll
    for (int ks = 0; ks < 8; ks++)
        Ag[ks] = *(const short8*)(pwg + (((ks * 4 + w) * 64 + lane) << 3));
    {   // sub-tile A
        f32x16 aG = {};
#pragma unroll
        for (int ks = 0; ks < 8; ks++) {
            short8 B = *(const short8*)(&xsA[cidx(ks * 2 + half, nn)]);
            aG = __builtin_amdgcn_mfma_f32_32x32x16_bf16(Ag[ks], B, aG, 0, 0, 0);
        }
        long node = row0 + nn;
        if (node < NNODES) {
#pragma unroll
            for (int q = 0; q < 4; q++) {
                int h0 = w * 32 + half * 4 + q * 8;
                uint2 d;
                d.x = pack2(sig_f(aG[q*4+0]) * sp_f(aTA[q*4+0]),
                            sig_f(aG[q*4+1]) * sp_f(aTA[q*4+1]));
                d.y = pack2(sig_f(aG[q*4+2]) * sp_f(aTA[q*4+2]),
                            sig_f(aG[q*4+3]) * sp_f(aTA[q*4+3]));
                *(uint2*)(M + node * HF + h0) = d;
            }
        }
    }
    {   // sub-tile B
        f32x16 aG = {};
#pragma unroll
        for (int ks = 0; ks < 8; ks++) {
            short8 B = *(const short8*)(&xsB[cidx(ks * 2 + half, nn)]);
            aG = __builtin_amdgcn_mfma_f32_32x32x16_bf16(Ag[ks], B, aG, 0, 0, 0);
        }
        long node = row0 + 32 + nn;
        if (node < NNODES) {
#pragma unroll
            for (int q = 0; q < 4; q++) {
                int h0 = w * 32 + half * 4 + q * 8;
                uint2 d;
                d.x = pack2(sig_f(aG[q*4+0]) * sp_f(aTB[q*4+0]),
                            sig_f(aG[q*4+1]) * sp_f(aTB[q*4+1]));
                d.y = pack2(sig_f(aG[q*4+2]) * sp_f(aTB[q*4+2]),
                            sig_f(aG[q*4+3]) * sp_f(aTB[q*4+3]));
                *(uint2*)(M + node * HF + h0) = d;
            }
        }
    }
}

// ---------------- conv0: embed fused (vectorized uint4); writes x and M ----------------
__global__ __launch_bounds__(256) void conv0_mfma(const int* __restrict__ nodes,
                                                  const void* __restrict__ emb,
                                                  u16* __restrict__ x,
                                                  const u16* __restrict__ pwg,
                                                  const u16* __restrict__ pwe1,
                                                  const u16* __restrict__ pwe2,
                                                  u16* __restrict__ M){
    __shared__ u16 xsA[16 * PLD], xsB[16 * PLD];   // 2 x 8,448 B
    __shared__ u16 usA[16 * PLD], usB[16 * PLD];   // 2 x 8,448 B
    const int t = threadIdx.x;
    const long row0 = (long)blockIdx.x * 64;
    const bool f32 = is_f32(emb);

    for (int i = t; i < 1024; i += 256) {          // (row r, chunk q): 16B each
        int r = i >> 4, q = i & 15;
        long node = row0 + r;
        uint4 d = make_uint4(0u, 0u, 0u, 0u);
        if (node < NNODES) {
            int v = nodes[node];
            if (f32) {
                float4 f0 = ((const float4*)emb)[(long)v * 32 + q * 2];
                float4 f1 = ((const float4*)emb)[(long)v * 32 + q * 2 + 1];
                d.x = pack2(f0.x, f0.y); d.y = pack2(f0.z, f0.w);
                d.z = pack2(f1.x, f1.y); d.w = pack2(f1.z, f1.w);
            } else {
                d = ((const uint4*)emb)[(long)v * 16 + q];
            }
            ((uint4*)x)[node * 16 + q] = d;
        }
        u16* xs = (r < 32) ? xsA : xsB;
        *(uint4*)(&xs[cidx(q, r & 31)]) = d;
    }
    __syncthreads();
    conv_phases2(xsA, xsB, usA, usB, pwg, pwe1, pwe2, M, row0);
}

// ---------------- conv: stages x from global; writes M ----------------
__global__ __launch_bounds__(256) void conv_mfma(const u16* __restrict__ x,
                                                 const u16* __restrict__ pwg,
                                                 const u16* __restrict__ pwe1,
                                                 const u16* __restrict__ pwe2,
                                                 u16* __restrict__ M){
    __shared__ u16 xsA[16 * PLD], xsB[16 * PLD];
    __shared__ u16 usA[16 * PLD], usB[16 * PLD];
    const int t = threadIdx.x;
    const long row0 = (long)blockIdx.x * 64;

    for (int i = t; i < 1024; i += 256) {
        int r = i >> 4, q = i & 15;
        long node = row0 + r;
        uint4 v = make_uint4(0u, 0u, 0u, 0u);
        if (node < NNODES) v = ((const uint4*)x)[node * 16 + q];
        u16* xs = (r < 32) ? xsA : xsB;
        *(uint4*)(&xs[cidx(q, r & 31)]) = v;
    }
    __syncthreads();
    conv_phases2(xsA, xsB, usA, usB, pwg, pwe1, pwe2, M, row0);
}

// ---------------- aggregation: x[v] += sp( sum_{e: tgt=v} M[src[e]] ) ----------------
// uint4 per lane, 16 lanes per node row, 4 nodes per wave, 4x-unrolled gather.
__global__ __launch_bounds__(256) void agg_kernel(const u16* __restrict__ M,
                                                  const int* __restrict__ row_ptr,
                                                  const int* __restrict__ counts,
                                                  const int* __restrict__ es,
                                                  u16* __restrict__ x){
    int wid = blockIdx.x * 4 + (threadIdx.x >> 6);
    int lane = threadIdx.x & 63;
    long v = (long)wid * 4 + (lane >> 4);
    int l = lane & 15;
    if (v >= NNODES) return;
    int start = row_ptr[v], cnt = counts[v];
    float a0=0.f,a1=0.f,a2=0.f,a3=0.f,a4=0.f,a5=0.f,a6=0.f,a7=0.f;
    float b0=0.f,b1=0.f,b2=0.f,b3=0.f,b4=0.f,b5=0.f,b6=0.f,b7=0.f;
    const uint4* Mu = (const uint4*)M;
    int e = 0;
    for (; e + 3 < cnt; e += 4) {
        int s0 = es[start + e],     s1 = es[start + e + 1];
        int s2 = es[start + e + 2], s3 = es[start + e + 3];
        uint4 u0 = Mu[(long)s0 * 16 + l];
        uint4 u1 = Mu[(long)s1 * 16 + l];
        uint4 u2 = Mu[(long)s2 * 16 + l];
        uint4 u3 = Mu[(long)s3 * 16 + l];
        a0 += bfu((u16)u0.x); a1 += bfu((u16)(u0.x >> 16));
        a2 += bfu((u16)u0.y); a3 += bfu((u16)(u0.y >> 16));
        a4 += bfu((u16)u0.z); a5 += bfu((u16)(u0.z >> 16));
        a6 += bfu((u16)u0.w); a7 += bfu((u16)(u0.w >> 16));
        b0 += bfu((u16)u1.x); b1 += bfu((u16)(u1.x >> 16));
        b2 += bfu((u16)u1.y); b3 += bfu((u16)(u1.y >> 16));
        b4 += bfu((u16)u1.z); b5 += bfu((u16)(u1.z >> 16));
        b6 += bfu((u16)u1.w); b7 += bfu((u16)(u1.w >> 16));
        a0 += bfu((u16)u2.x); a1 += bfu((u16)(u2.x >> 16));
        a2 += bfu((u16)u2.y); a3 += bfu((u16)(u2.y >> 16));
        a4 += bfu((u16)u2.z); a5 += bfu((u16)(u2.z >> 16));
        a6 += bfu((u16)u2.w); a7 += bfu((u16)(u2.w >> 16));
        b0 += bfu((u16)u3.x); b1 += bfu((u16)(u3.x >> 16));
        b2 += bfu((u16)u3.y); b3 += bfu((u16)(u3.y >> 16));
        b4 += bfu((u16)u3.z); b5 += bfu((u16)(u3.z >> 16));
        b6 += bfu((u16)u3.w); b7 += bfu((u16)(u3.w >> 16));
    }
    for (; e < cnt; e++) {
        int s0 = es[start + e];
        uint4 u0 = Mu[(long)s0 * 16 + l];
        a0 += bfu((u16)u0.x); a1 += bfu((u16)(u0.x >> 16));
        a2 += bfu((u16)u0.y); a3 += bfu((u16)(u0.y >> 16));
        a4 += bfu((u16)u0.z); a5 += bfu((u16)(u0.z >> 16));
        a6 += bfu((u16)u0.w); a7 += bfu((u16)(u0.w >> 16));
    }
    a0 += b0; a1 += b1; a2 += b2; a3 += b3;
    a4 += b4; a5 += b5; a6 += b6; a7 += b7;
    uint4* xu = (uint4*)x;
    uint4 xv = xu[v * 16 + l];
    xv.x = pack2(bfu((u16)xv.x) + sp_f(a0), bfu((u16)(xv.x >> 16)) + sp_f(a1));
    xv.y = pack2(bfu((u16)xv.y) + sp_f(a2), bfu((u16)(xv.y >> 16)) + sp_f(a3));
    xv.z = pack2(bfu((u16)xv.z) + sp_f(a4), bfu((u16)(xv.z >> 16)) + sp_f(a5));
    xv.w = pack2(bfu((u16)xv.w) + sp_f(a6), bfu((u16)(xv.w >> 16)) + sp_f(a7));
    xu[v * 16 + l] = xv;
}

// ---------------- pooling: xsum[g] = sum of x rows of graph g (atomic flush) ----------------
__global__ __launch_bounds__(256) void pool_kernel(const u16* __restrict__ x,
                                                   const int* __restrict__ gidx,
                                                   float* __restrict__ xsum){
    int wave = blockIdx.x * 4 + (threadIdx.x >> 6);
    int lane = threadIdx.x & 63;
    long base = (long)wave * 64;
    if (base >= NNODES) return;
    long end = base + 64; if (end > NNODES) end = NNODES;
    const unsigned* xu = (const unsigned*)x;
    int gcur = gidx[base];
    float a0 = 0.f, a1 = 0.f;
    for (long v = base; v < end; v++) {
        int g = gidx[v];                           // wave-uniform
        if (g != gcur) {
            atomicAdd(&xsum[gcur * HF + lane * 2 + 0], a0);
            atomicAdd(&xsum[gcur * HF + lane * 2 + 1], a1);
            a0 = a1 = 0.f; gcur = g;
        }
        unsigned u = xu[v * 64 + lane];
        a0 += bfu((u16)u);
        a1 += bfu((u16)(u >> 16));
    }
    atomicAdd(&xsum[gcur * HF + lane * 2 + 0], a0);
    atomicAdd(&xsum[gcur * HF + lane * 2 + 1], a1);
}

// ---------------- head via transposed 16x16 MFMA, bf16 hi+lo activations ----------------
__global__ __launch_bounds__(256) void head_mfma(const float* __restrict__ xsum,
                                                 const void* __restrict__ ncnt,
                                                 const u16* __restrict__ pwp,
                                                 const u16* __restrict__ pf1,
                                                 const u16* __restrict__ pf2,
                                                 const void* __restrict__ bfc1,
                                                 const void* __restrict__ bfc2,
                                                 const void* __restrict__ Wr,
                                                 const void* __restrict__ br,
                                                 void* __restrict__ out,
                                                 const void* __restrict__ probe){
    __shared__ u16 hibuf[2][GB][136];
    __shared__ u16 lobuf[2][GB][136];
    const int t = threadIdx.x;
    const int w = t >> 6, lane = t & 63;
    const int quad = lane >> 4, nr = lane & 15;
    const bool f32 = is_f32(probe);
    const int g0 = blockIdx.x * GB;

    for (int i = t; i < GB * 64; i += 256) {
        int g = i >> 6, c = (i & 63) * 2;
        float f0 = xsum[(g0 + g) * HF + c], f1 = xsum[(g0 + g) * HF + c + 1];
        u16 h0 = f2bf(f0), h1 = f2bf(f1);
        *(unsigned*)&hibuf[0][g][c] = (unsigned)h0 | ((unsigned)h1 << 16);
        *(unsigned*)&lobuf[0][g][c] = pack2(f0 - bfu(h0), f1 - bfu(h1));
    }
    __syncthreads();

    float rc[2];
#pragma unroll
    for (int nt = 0; nt < 2; nt++) rc[nt] = RCP1(lf(ncnt, g0 + nt * 16 + nr, f32));

    int cur = 0;
    for (int layer = 0; layer < 3; layer++) {
        const u16* pw = (layer == 0) ? pwp : (layer == 1) ? pf1 : pf2;
        const void* bias = (layer == 1) ? bfc1 : bfc2;
        int nxt = cur ^ 1;
#pragma unroll
        for (int c = 0; c < 2; c++) {
            int et = w * 2 + c;
            short8 A[4];
#pragma unroll
            for (int kt = 0; kt < 4; kt++)
                A[kt] = *(const short8*)(pw + (((kt * 8 + et) * 64 + lane) << 3));
#pragma unroll
            for (int nt = 0; nt < 2; nt++) {
                f32x4 acc = {0.f, 0.f, 0.f, 0.f};
#pragma unroll
                for (int kt = 0; kt < 4; kt++) {
                    short8 bh = *(const short8*)(&hibuf[cur][nt * 16 + nr][kt * 32 + quad * 8]);
                    short8 bl = *(const short8*)(&lobuf[cur][nt * 16 + nr][kt * 32 + quad * 8]);
                    acc = __builtin_amdgcn_mfma_f32_16x16x32_bf16(A[kt], bh, acc, 0, 0, 0);
                    acc = __builtin_amdgcn_mfma_f32_16x16x32_bf16(A[kt], bl, acc, 0, 0, 0);
                }
                int feat0 = et * 16 + quad * 4;
                float f[4];
#pragma unroll
                for (int r = 0; r < 4; r++) {
                    float a = (layer == 0) ? acc[r] * rc[nt]
                                           : acc[r] + lf(bias, feat0 + r, f32);
                    f[r] = sp_f(a);
                }
                u16 h[4]; float lo[4];
#pragma unroll
                for (int r = 0; r < 4; r++) { h[r] = f2bf(f[r]); lo[r] = f[r] - bfu(h[r]); }
                uint2 dh, dl;
                dh.x = (unsigned)h[0] | ((unsigned)h[1] << 16);
                dh.y = (unsigned)h[2] | ((unsigned)h[3] << 16);
                dl.x = pack2(lo[0], lo[1]);
                dl.y = pack2(lo[2], lo[3]);
                *(uint2*)&hibuf[nxt][nt * 16 + nr][feat0] = dh;
                *(uint2*)&lobuf[nxt][nt * 16 + nr][feat0] = dl;
            }
        }
        __syncthreads();
        cur = nxt;
    }

    int g = t >> 3, sub = t & 7;
    float p = 0.f;
    for (int k = sub * 16; k < sub * 16 + 16; k++) {
        float v = bfu(hibuf[cur][g][k]) + bfu(lobuf[cur][g][k]);
        p += v * lf(Wr, k, f32);
    }
    p += __shfl_down(p, 4, 64);
    p += __shfl_down(p, 2, 64);
    p += __shfl_down(p, 1, 64);
    if (sub == 0) {
        float res = p + lf(br, 0, f32);
        if (f32) ((float*)out)[g0 + g] = res;
        else     ((u16*)out)[g0 + g]  = f2bf(res);
    }
}

extern "C" void kernel_launch(void* const* d_in, const int* in_sizes, int n_in,
                              void* d_out, int out_size, void* d_ws, size_t ws_size,
                              hipStream_t stream) {
    const int* nodes = (const int*)d_in[0];
    const int* esrc  = (const int*)d_in[1];
    const int* etgt  = (const int*)d_in[2];
    const int* gidx  = (const int*)d_in[3];

    size_t off = 0;
    char* w = (char*)d_ws;
    auto take = [&](size_t bytes) -> void* {
        void* p = w + off;
        off = (off + bytes + 255) & ~(size_t)255;
        return p;
    };

    u16* pwg     = (u16*)take((size_t)3 * HF * HF * 2);
    u16* pwe1    = (u16*)take((size_t)3 * HF * EF * 2);
    u16* pwe2    = (u16*)take((size_t)3 * EF * HF * 2);
    u16* pwp     = (u16*)take((size_t)HF * HF * 2);
    u16* pf1     = (u16*)take((size_t)HF * HF * 2);
    u16* pf2     = (u16*)take((size_t)HF * HF * 2);
    int* counts  = (int*)take((size_t)NNODES * 4);
    int* row_ptr = (int*)take((size_t)NNODES * 4);
    int* cursor  = (int*)take((size_t)NNODES * 4);
    int* es      = (int*)take((size_t)NEDGES * 4);
    int* bsums   = (int*)take(2048);
    int* boffs   = (int*)take(2048);
    float* xsum  = (float*)take((size_t)NGRAPHS * HF * 4);
    u16* x       = (u16*)take((size_t)NNODES * HF * 2);
    u16* M       = (u16*)take((size_t)NNODES * HF * 2);

    hipMemsetAsync(counts, 0, (size_t)NNODES * 4, stream);

    // prep: conv repack (960) + head repack (192) + count (2344) + xsum zero (64)
    prep_kernel<<<3560, 256, 0, stream>>>(d_in[6], d_in[7], d_in[8],
                                          d_in[9], d_in[10], d_in[12],
                                          pwg, pwe1, pwe2, pwp, pf1, pf2,
                                          d_in[5], etgt, counts, xsum);

    const int NB_SCAN = (NNODES + 255) / 256;      // 391
    const int NB_EDGE = (NEDGES + 255) / 256;      // 2344
    scan1_kernel<<<NB_SCAN, 256, 0, stream>>>(counts, row_ptr, bsums);
    scan2_kernel<<<1, 512, 0, stream>>>(bsums, boffs, NB_SCAN);
    scan3_kernel<<<NB_SCAN, 256, 0, stream>>>(row_ptr, boffs, cursor);
    fill_kernel<<<NB_EDGE, 256, 0, stream>>>(esrc, etgt, cursor, es);

    const int NBC = (NNODES + 63) / 64;            // 1563 (64 nodes/block)
    const int NBA = (NNODES + 15) / 16;            // 6250
    conv0_mfma<<<NBC, 256, 0, stream>>>(nodes, d_in[5], x, pwg, pwe1, pwe2, M);
    agg_kernel<<<NBA, 256, 0, stream>>>(M, row_ptr, counts, es, x);
    conv_mfma<<<NBC, 256, 0, stream>>>(x,
        pwg + (size_t)1 * HF * HF, pwe1 + (size_t)1 * HF * EF, pwe2 + (size_t)1 * EF * HF, M);
    agg_kernel<<<NBA, 256, 0, stream>>>(M, row_ptr, counts, es, x);
    conv_mfma<<<NBC, 256, 0, stream>>>(x,
        pwg + (size_t)2 * HF * HF, pwe1 + (size_t)2 * HF * EF, pwe2 + (size_t)2 * EF * HF, M);
    agg_kernel<<<NBA, 256, 0, stream>>>(M, row_ptr, counts, es, x);

    pool_kernel<<<(NNODES + 255) / 256, 256, 0, stream>>>(x, gidx, xsum);
    head_mfma<<<NGRAPHS / GB, 256, 0, stream>>>(xsum, d_in[4], pwp, pf1, pf2,
                                                d_in[11], d_in[13], d_in[14], d_in[15],
                                                d_out, d_in[5]);
}

// Round 2
// 392.590 us; speedup vs baseline: 1.0132x; 1.0064x over previous
//
#include <hip/hip_runtime.h>
#include <hip/hip_bf16.h>

typedef unsigned short u16;
typedef __attribute__((ext_vector_type(8))) short short8;
typedef __attribute__((ext_vector_type(4))) float f32x4;
typedef __attribute__((ext_vector_type(16))) float f32x16;
typedef __attribute__((ext_vector_type(2))) __bf16 bf16x2;

#define NNODES 100000
#define NEDGES 600000
#define NGRAPHS 512
#define HF 128
#define EF 256
#define GB 32       // graphs per head block

// chunk-major LDS planes, 32-node tiles: plane = 32 rows x 16B + 16B pad
// -> stride 264 u16 (528 B = 132 dwords == 4 banks mod 32)
#define PLD 264
__device__ __forceinline__ int cidx(int chunk, int row){ return chunk * PLD + row * 8; }

__device__ __forceinline__ float bfu(u16 u){ return __uint_as_float(((unsigned)u) << 16); }
__device__ __forceinline__ u16 f2bf(float f){
    unsigned u = __float_as_uint(f);
    unsigned r = (u + 0x7fff + ((u >> 16) & 1)) >> 16;
    return (u16)r;
}
// HW packed f32->bf16 RNE (v_cvt_pk_bf16_f32 on gfx950)
__device__ __forceinline__ unsigned pack2(float a, float b){
    bf16x2 v = { (__bf16)a, (__bf16)b };
    return __builtin_bit_cast(unsigned, v);
}

#if __has_builtin(__builtin_amdgcn_rcpf)
#define RCP1(x) __builtin_amdgcn_rcpf(x)
#else
#define RCP1(x) (1.f / (x))
#endif

// cheap softplus: log(1+exp(x)) direct — safe for |x| << 80 (values here <~20)
__device__ __forceinline__ float sp_f(float x){
    return __logf(1.f + __expf(x));
}
__device__ __forceinline__ float sig_f(float x){
    return RCP1(1.f + __expf(-x));
}
__device__ __forceinline__ float lf(const void* p, long i, bool f32){
    return f32 ? ((const float*)p)[i] : bfu(((const u16*)p)[i]);
}

// in-register dtype detection: probe 256 u16 of the embed table as bf16
__device__ __forceinline__ bool is_f32(const void* probe){
    const u16* p = (const u16*)probe;
    int lane = threadIdx.x & 63;
    int c = 0;
#pragma unroll
    for (int i = 0; i < 4; i++) c += (fabsf(bfu(p[lane * 4 + i])) > 1.0f) ? 1 : 0;
#pragma unroll
    for (int off = 32; off; off >>= 1) c += __shfl_xor(c, off, 64);
    return c > 8;
}

// ---------------- prep: weight repack + edge count + xsum zero ----------------
// conv weights -> 32x32x16 A-frag order: P[ks][nt32][lane][8]; lane l holds
//   W[k = ks*16 + (l>>5)*8 + j][n = nt32*32 + (l&31)], j=0..7  (W^T as A operand)
// head weights -> 16x16x32 frag order.
// blocks [0,960): conv; [960,1152): head; [1152,3496): edge count;
// [3496,3560): zero xsum (64 blocks x 256 x float4)
__global__ __launch_bounds__(256) void prep_kernel(const void* __restrict__ wg,
                                                   const void* __restrict__ we1,
                                                   const void* __restrict__ we2,
                                                   const void* __restrict__ wp,
                                                   const void* __restrict__ wfc1,
                                                   const void* __restrict__ wfc2,
                                                   u16* __restrict__ pwg,
                                                   u16* __restrict__ pwe1,
                                                   u16* __restrict__ pwe2,
                                                   u16* __restrict__ pwp,
                                                   u16* __restrict__ pf1,
                                                   u16* __restrict__ pf2,
                                                   const void* __restrict__ emb,
                                                   const int* __restrict__ tgt,
                                                   int* __restrict__ counts,
                                                   float* __restrict__ xsum){
    int b = blockIdx.x, t = threadIdx.x;
    if (b < 960) {
        bool f32 = is_f32(emb);
        int i = b * 256 + t;                       // < 3*81920
        int c = i / 81920, r = i % 81920;
        const void* src; u16* dst; int N, KN, l;
        if (r < 16384)      { src = wg;  dst = pwg;  N = HF; KN = 16384; l = r; }
        else if (r < 49152) { src = we1; dst = pwe1; N = EF; KN = 32768; l = r - 16384; }
        else                { src = we2; dst = pwe2; N = HF; KN = 32768; l = r - 49152; }
        int j = l & 7, lane = (l >> 3) & 63, rest = l >> 9;
        int NT = N >> 5;
        int nt = rest % NT, ks = rest / NT;
        int k = ks * 16 + (lane >> 5) * 8 + j;
        int n = nt * 32 + (lane & 31);
        long base = (long)c * KN;
        dst[base + l] = f2bf(lf(src, base + (long)k * N + n, f32));
    } else if (b < 1152) {
        bool f32 = is_f32(emb);
        int i = (b - 960) * 256 + t;               // < 3*16384
        int c = i / 16384, l = i % 16384;
        const void* src = (c == 0) ? wp : (c == 1) ? wfc1 : wfc2;
        u16* dst = (c == 0) ? pwp : (c == 1) ? pf1 : pf2;
        int j = l & 7, lane = (l >> 3) & 63, rest = l >> 9;
        int nt = rest & 7, kt = rest >> 3;         // 16x16 layout, N=128
        int k = kt * 32 + (lane >> 4) * 8 + j;
        int n = nt * 16 + (lane & 15);
        dst[l] = f2bf(lf(src, (long)k * HF + n, f32));
    } else if (b < 3496) {
        int e = (b - 1152) * 256 + t;
        if (e < NEDGES) atomicAdd(&counts[tgt[e]], 1);
    } else {
        int i = (b - 3496) * 256 + t;              // < 16384 float4s
        ((float4*)xsum)[i] = make_float4(0.f, 0.f, 0.f, 0.f);
    }
}

// ---------------- CSR build ----------------
__global__ __launch_bounds__(256) void scan1_kernel(const int* __restrict__ counts,
                                                    int* __restrict__ row_ptr,
                                                    int* __restrict__ bsums){
    __shared__ int s[256];
    int t = threadIdx.x;
    int i = blockIdx.x * 256 + t;
    int v = (i < NNODES) ? counts[i] : 0;
    s[t] = v; __syncthreads();
    for (int off = 1; off < 256; off <<= 1) {
        int a = (t >= off) ? s[t - off] : 0;
        __syncthreads();
        s[t] += a;
        __syncthreads();
    }
    if (i < NNODES) row_ptr[i] = s[t] - v;
    if (t == 255) bsums[blockIdx.x] = s[255];
}

__global__ __launch_bounds__(512) void scan2_kernel(const int* __restrict__ bsums,
                                                    int* __restrict__ boffs, int nb){
    __shared__ int s[512];
    int t = threadIdx.x;
    int v = (t < nb) ? bsums[t] : 0;
    s[t] = v; __syncthreads();
    for (int off = 1; off < 512; off <<= 1) {
        int a = (t >= off) ? s[t - off] : 0;
        __syncthreads();
        s[t] += a;
        __syncthreads();
    }
    if (t < nb) boffs[t] = s[t] - v;
}

__global__ __launch_bounds__(256) void scan3_kernel(int* __restrict__ row_ptr,
                                                    const int* __restrict__ boffs,
                                                    int* __restrict__ cursor){
    int i = blockIdx.x * 256 + threadIdx.x;
    if (i < NNODES) {
        int r = row_ptr[i] + boffs[blockIdx.x];
        row_ptr[i] = r;
        cursor[i]  = r;
    }
}

__global__ __launch_bounds__(256) void fill_kernel(const int* __restrict__ src,
                                                   const int* __restrict__ tgt,
                                                   int* __restrict__ cursor,
                                                   int* __restrict__ es){
    int e = blockIdx.x * 256 + threadIdx.x;
    if (e < NEDGES) {
        int pos = atomicAdd(&cursor[tgt[e]], 1);
        es[pos] = src[e];
    }
}

// ========== conv MFMA phases, 32x32x16, 32-node tile, FULL U in LDS ==========
// One xs sweep computes BOTH ef-tiles per wave (et = w and w+4; each B-read
// feeds 2 MFMAs), storing the full 256x32 U (32 planes, 16.9 KB). C-phase
// then runs K=256 in one 16-step loop. 2 barriers/block (was 4).
// LDS: xs 8.45 KB + us 16.9 KB = 25.3 KB -> 6 blocks/CU (24 waves/CU).
// __launch_bounds__(256,6) caps VGPR at ~84 so registers match LDS residency.
// Accumulation order bit-identical to the half-pass version:
//   U: ks 0..7 per et; C: jj 0..15 == (p0 j0..7, p1 j0..7); G unchanged.
__device__ __forceinline__ void conv_phases(u16* xs, u16* us,
                                            const u16* __restrict__ pwg,
                                            const u16* __restrict__ pwe1,
                                            const u16* __restrict__ pwe2,
                                            u16* __restrict__ M, long row0){
    const int t = threadIdx.x;
    const int w = t >> 6, lane = t & 63;
    const int half = lane >> 5, nn = lane & 31;

    // ---- U phase: wave w owns ef-tiles et = w and et = w+4 ----
    f32x16 acc0 = {}, acc1 = {};
#pragma unroll
    for (int ks = 0; ks < 8; ks++) {
        short8 A0 = *(const short8*)(pwe1 + (((ks * 8 + w) * 64 + lane) << 3));
        short8 A1 = *(const short8*)(pwe1 + (((ks * 8 + w + 4) * 64 + lane) << 3));
        short8 B  = *(const short8*)(&xs[cidx(ks * 2 + half, nn)]);
        acc0 = __builtin_amdgcn_mfma_f32_32x32x16_bf16(A0, B, acc0, 0, 0, 0);
        acc1 = __builtin_amdgcn_mfma_f32_32x32x16_bf16(A1, B, acc1, 0, 0, 0);
    }
#pragma unroll
    for (int q = 0; q < 4; q++) {
        uint2 d;
        d.x = pack2(sp_f(acc0[q*4+0]), sp_f(acc0[q*4+1]));
        d.y = pack2(sp_f(acc0[q*4+2]), sp_f(acc0[q*4+3]));
        *(uint2*)(&us[cidx(w * 4 + q, nn) + half * 4]) = d;
        uint2 e;
        e.x = pack2(sp_f(acc1[q*4+0]), sp_f(acc1[q*4+1]));
        e.y = pack2(sp_f(acc1[q*4+2]), sp_f(acc1[q*4+3]));
        *(uint2*)(&us[cidx(16 + w * 4 + q, nn) + half * 4]) = e;
    }
    __syncthreads();

    // ---- C phase: aT = We2^T[h-tile w] @ U, K=256 in 16 steps ----
    f32x16 aT = {};
#pragma unroll
    for (int jj = 0; jj < 16; jj++) {
        short8 Ac = *(const short8*)(pwe2 + (((jj * 4 + w) * 64 + lane) << 3));
        short8 B  = *(const short8*)(&us[cidx(jj * 2 + half, nn)]);
        aT = __builtin_amdgcn_mfma_f32_32x32x16_bf16(Ac, B, aT, 0, 0, 0);
    }

    // ---- G phase: aG = Wg^T[h-tile w] @ x^T; fused gate + M write ----
    f32x16 aG = {};
#pragma unroll
    for (int ks = 0; ks < 8; ks++) {
        short8 Ag = *(const short8*)(pwg + (((ks * 4 + w) * 64 + lane) << 3));
        short8 B  = *(const short8*)(&xs[cidx(ks * 2 + half, nn)]);
        aG = __builtin_amdgcn_mfma_f32_32x32x16_bf16(Ag, B, aG, 0, 0, 0);
    }
    long node = row0 + nn;                         // 3125*32 == NNODES exactly
#pragma unroll
    for (int q = 0; q < 4; q++) {
        int h0 = w * 32 + half * 4 + q * 8;
        uint2 d;
        d.x = pack2(sig_f(aG[q*4+0]) * sp_f(aT[q*4+0]),
                    sig_f(aG[q*4+1]) * sp_f(aT[q*4+1]));
        d.y = pack2(sig_f(aG[q*4+2]) * sp_f(aT[q*4+2]),
                    sig_f(aG[q*4+3]) * sp_f(aT[q*4+3]));
        *(uint2*)(M + node * HF + h0) = d;
    }
}

// ---------------- conv0: embed fused (vectorized uint4); writes x and M ----------------
__global__ __launch_bounds__(256, 6) void conv0_mfma(const int* __restrict__ nodes,
                                                     const void* __restrict__ emb,
                                                     u16* __restrict__ x,
                                                     const u16* __restrict__ pwg,
                                                     const u16* __restrict__ pwe1,
                                                     const u16* __restrict__ pwe2,
                                                     u16* __restrict__ M){
    __shared__ u16 xs[16 * PLD];   //  8,448 B
    __shared__ u16 us[32 * PLD];   // 16,896 B
    const int t = threadIdx.x;
    const long row0 = (long)blockIdx.x * 32;
    const bool f32 = is_f32(emb);

    for (int i = t; i < 512; i += 256) {           // (row r, chunk q): 16B each
        int r = i >> 4, q = i & 15;
        long node = row0 + r;                      // always < NNODES (exact fit)
        int v = nodes[node];
        uint4 d;
        if (f32) {
            float4 f0 = ((const float4*)emb)[(long)v * 32 + q * 2];
            float4 f1 = ((const float4*)emb)[(long)v * 32 + q * 2 + 1];
            d.x = pack2(f0.x, f0.y); d.y = pack2(f0.z, f0.w);
            d.z = pack2(f1.x, f1.y); d.w = pack2(f1.z, f1.w);
        } else {
            d = ((const uint4*)emb)[(long)v * 16 + q];
        }
        ((uint4*)x)[node * 16 + q] = d;
        *(uint4*)(&xs[cidx(q, r)]) = d;
    }
    __syncthreads();
    conv_phases(xs, us, pwg, pwe1, pwe2, M, row0);
}

// ---------------- conv: stages x from global; writes M ----------------
__global__ __launch_bounds__(256, 6) void conv_mfma(const u16* __restrict__ x,
                                                    const u16* __restrict__ pwg,
                                                    const u16* __restrict__ pwe1,
                                                    const u16* __restrict__ pwe2,
                                                    u16* __restrict__ M){
    __shared__ u16 xs[16 * PLD];
    __shared__ u16 us[32 * PLD];
    const int t = threadIdx.x;
    const long row0 = (long)blockIdx.x * 32;

    for (int i = t; i < 512; i += 256) {
        int r = i >> 4, q = i & 15;
        long node = row0 + r;                      // always < NNODES (exact fit)
        uint4 v = ((const uint4*)x)[node * 16 + q];
        *(uint4*)(&xs[cidx(q, r)]) = v;
    }
    __syncthreads();
    conv_phases(xs, us, pwg, pwe1, pwe2, M, row0);
}

// ---------------- aggregation: x[v] += sp( sum_{e: tgt=v} M[src[e]] ) ----------------
// uint4 per lane, 16 lanes per node row, 4 nodes per wave, 4x-unrolled gather.
__global__ __launch_bounds__(256) void agg_kernel(const u16* __restrict__ M,
                                                  const int* __restrict__ row_ptr,
                                                  const int* __restrict__ counts,
                                                  const int* __restrict__ es,
                                                  u16* __restrict__ x){
    int wid = blockIdx.x * 4 + (threadIdx.x >> 6);
    int lane = threadIdx.x & 63;
    long v = (long)wid * 4 + (lane >> 4);
    int l = lane & 15;
    if (v >= NNODES) return;
    int start = row_ptr[v], cnt = counts[v];
    float a0=0.f,a1=0.f,a2=0.f,a3=0.f,a4=0.f,a5=0.f,a6=0.f,a7=0.f;
    float b0=0.f,b1=0.f,b2=0.f,b3=0.f,b4=0.f,b5=0.f,b6=0.f,b7=0.f;
    const uint4* Mu = (const uint4*)M;
    int e = 0;
    for (; e + 3 < cnt; e += 4) {
        int s0 = es[start + e],     s1 = es[start + e + 1];
        int s2 = es[start + e + 2], s3 = es[start + e + 3];
        uint4 u0 = Mu[(long)s0 * 16 + l];
        uint4 u1 = Mu[(long)s1 * 16 + l];
        uint4 u2 = Mu[(long)s2 * 16 + l];
        uint4 u3 = Mu[(long)s3 * 16 + l];
        a0 += bfu((u16)u0.x); a1 += bfu((u16)(u0.x >> 16));
        a2 += bfu((u16)u0.y); a3 += bfu((u16)(u0.y >> 16));
        a4 += bfu((u16)u0.z); a5 += bfu((u16)(u0.z >> 16));
        a6 += bfu((u16)u0.w); a7 += bfu((u16)(u0.w >> 16));
        b0 += bfu((u16)u1.x); b1 += bfu((u16)(u1.x >> 16));
        b2 += bfu((u16)u1.y); b3 += bfu((u16)(u1.y >> 16));
        b4 += bfu((u16)u1.z); b5 += bfu((u16)(u1.z >> 16));
        b6 += bfu((u16)u1.w); b7 += bfu((u16)(u1.w >> 16));
        a0 += bfu((u16)u2.x); a1 += bfu((u16)(u2.x >> 16));
        a2 += bfu((u16)u2.y); a3 += bfu((u16)(u2.y >> 16));
        a4 += bfu((u16)u2.z); a5 += bfu((u16)(u2.z >> 16));
        a6 += bfu((u16)u2.w); a7 += bfu((u16)(u2.w >> 16));
        b0 += bfu((u16)u3.x); b1 += bfu((u16)(u3.x >> 16));
        b2 += bfu((u16)u3.y); b3 += bfu((u16)(u3.y >> 16));
        b4 += bfu((u16)u3.z); b5 += bfu((u16)(u3.z >> 16));
        b6 += bfu((u16)u3.w); b7 += bfu((u16)(u3.w >> 16));
    }
    for (; e < cnt; e++) {
        int s0 = es[start + e];
        uint4 u0 = Mu[(long)s0 * 16 + l];
        a0 += bfu((u16)u0.x); a1 += bfu((u16)(u0.x >> 16));
        a2 += bfu((u16)u0.y); a3 += bfu((u16)(u0.y >> 16));
        a4 += bfu((u16)u0.z); a5 += bfu((u16)(u0.z >> 16));
        a6 += bfu((u16)u0.w); a7 += bfu((u16)(u0.w >> 16));
    }
    a0 += b0; a1 += b1; a2 += b2; a3 += b3;
    a4 += b4; a5 += b5; a6 += b6; a7 += b7;
    uint4* xu = (uint4*)x;
    uint4 xv = xu[v * 16 + l];
    xv.x = pack2(bfu((u16)xv.x) + sp_f(a0), bfu((u16)(xv.x >> 16)) + sp_f(a1));
    xv.y = pack2(bfu((u16)xv.y) + sp_f(a2), bfu((u16)(xv.y >> 16)) + sp_f(a3));
    xv.z = pack2(bfu((u16)xv.z) + sp_f(a4), bfu((u16)(xv.z >> 16)) + sp_f(a5));
    xv.w = pack2(bfu((u16)xv.w) + sp_f(a6), bfu((u16)(xv.w >> 16)) + sp_f(a7));
    xu[v * 16 + l] = xv;
}

// ---------------- pooling: xsum[g] = sum of x rows of graph g (atomic flush) ----------------
__global__ __launch_bounds__(256) void pool_kernel(const u16* __restrict__ x,
                                                   const int* __restrict__ gidx,
                                                   float* __restrict__ xsum){
    int wave = blockIdx.x * 4 + (threadIdx.x >> 6);
    int lane = threadIdx.x & 63;
    long base = (long)wave * 64;
    if (base >= NNODES) return;
    long end = base + 64; if (end > NNODES) end = NNODES;
    const unsigned* xu = (const unsigned*)x;
    int gcur = gidx[base];
    float a0 = 0.f, a1 = 0.f;
    for (long v = base; v < end; v++) {
        int g = gidx[v];                           // wave-uniform
        if (g != gcur) {
            atomicAdd(&xsum[gcur * HF + lane * 2 + 0], a0);
            atomicAdd(&xsum[gcur * HF + lane * 2 + 1], a1);
            a0 = a1 = 0.f; gcur = g;
        }
        unsigned u = xu[v * 64 + lane];
        a0 += bfu((u16)u);
        a1 += bfu((u16)(u >> 16));
    }
    atomicAdd(&xsum[gcur * HF + lane * 2 + 0], a0);
    atomicAdd(&xsum[gcur * HF + lane * 2 + 1], a1);
}

// ---------------- head via transposed 16x16 MFMA, bf16 hi+lo activations ----------------
__global__ __launch_bounds__(256) void head_mfma(const float* __restrict__ xsum,
                                                 const void* __restrict__ ncnt,
                                                 const u16* __restrict__ pwp,
                                                 const u16* __restrict__ pf1,
                                                 const u16* __restrict__ pf2,
                                                 const void* __restrict__ bfc1,
                                                 const void* __restrict__ bfc2,
                                                 const void* __restrict__ Wr,
                                                 const void* __restrict__ br,
                                                 void* __restrict__ out,
                                                 const void* __restrict__ probe){
    __shared__ u16 hibuf[2][GB][136];
    __shared__ u16 lobuf[2][GB][136];
    const int t = threadIdx.x;
    const int w = t >> 6, lane = t & 63;
    const int quad = lane >> 4, nr = lane & 15;
    const bool f32 = is_f32(probe);
    const int g0 = blockIdx.x * GB;

    for (int i = t; i < GB * 64; i += 256) {
        int g = i >> 6, c = (i & 63) * 2;
        float f0 = xsum[(g0 + g) * HF + c], f1 = xsum[(g0 + g) * HF + c + 1];
        u16 h0 = f2bf(f0), h1 = f2bf(f1);
        *(unsigned*)&hibuf[0][g][c] = (unsigned)h0 | ((unsigned)h1 << 16);
        *(unsigned*)&lobuf[0][g][c] = pack2(f0 - bfu(h0), f1 - bfu(h1));
    }
    __syncthreads();

    float rc[2];
#pragma unroll
    for (int nt = 0; nt < 2; nt++) rc[nt] = RCP1(lf(ncnt, g0 + nt * 16 + nr, f32));

    int cur = 0;
    for (int layer = 0; layer < 3; layer++) {
        const u16* pw = (layer == 0) ? pwp : (layer == 1) ? pf1 : pf2;
        const void* bias = (layer == 1) ? bfc1 : bfc2;
        int nxt = cur ^ 1;
#pragma unroll
        for (int c = 0; c < 2; c++) {
            int et = w * 2 + c;
            short8 A[4];
#pragma unroll
            for (int kt = 0; kt < 4; kt++)
                A[kt] = *(const short8*)(pw + (((kt * 8 + et) * 64 + lane) << 3));
#pragma unroll
            for (int nt = 0; nt < 2; nt++) {
                f32x4 acc = {0.f, 0.f, 0.f, 0.f};
#pragma unroll
                for (int kt = 0; kt < 4; kt++) {
                    short8 bh = *(const short8*)(&hibuf[cur][nt * 16 + nr][kt * 32 + quad * 8]);
                    short8 bl = *(const short8*)(&lobuf[cur][nt * 16 + nr][kt * 32 + quad * 8]);
                    acc = __builtin_amdgcn_mfma_f32_16x16x32_bf16(A[kt], bh, acc, 0, 0, 0);
                    acc = __builtin_amdgcn_mfma_f32_16x16x32_bf16(A[kt], bl, acc, 0, 0, 0);
                }
                int feat0 = et * 16 + quad * 4;
                float f[4];
#pragma unroll
                for (int r = 0; r < 4; r++) {
                    float a = (layer == 0) ? acc[r] * rc[nt]
                                           : acc[r] + lf(bias, feat0 + r, f32);
                    f[r] = sp_f(a);
                }
                u16 h[4]; float lo[4];
#pragma unroll
                for (int r = 0; r < 4; r++) { h[r] = f2bf(f[r]); lo[r] = f[r] - bfu(h[r]); }
                uint2 dh, dl;
                dh.x = (unsigned)h[0] | ((unsigned)h[1] << 16);
                dh.y = (unsigned)h[2] | ((unsigned)h[3] << 16);
                dl.x = pack2(lo[0], lo[1]);
                dl.y = pack2(lo[2], lo[3]);
                *(uint2*)&hibuf[nxt][nt * 16 + nr][feat0] = dh;
                *(uint2*)&lobuf[nxt][nt * 16 + nr][feat0] = dl;
            }
        }
        __syncthreads();
        cur = nxt;
    }

    int g = t >> 3, sub = t & 7;
    float p = 0.f;
    for (int k = sub * 16; k < sub * 16 + 16; k++) {
        float v = bfu(hibuf[cur][g][k]) + bfu(lobuf[cur][g][k]);
        p += v * lf(Wr, k, f32);
    }
    p += __shfl_down(p, 4, 64);
    p += __shfl_down(p, 2, 64);
    p += __shfl_down(p, 1, 64);
    if (sub == 0) {
        float res = p + lf(br, 0, f32);
        if (f32) ((float*)out)[g0 + g] = res;
        else     ((u16*)out)[g0 + g]  = f2bf(res);
    }
}

extern "C" void kernel_launch(void* const* d_in, const int* in_sizes, int n_in,
                              void* d_out, int out_size, void* d_ws, size_t ws_size,
                              hipStream_t stream) {
    const int* nodes = (const int*)d_in[0];
    const int* esrc  = (const int*)d_in[1];
    const int* etgt  = (const int*)d_in[2];
    const int* gidx  = (const int*)d_in[3];

    size_t off = 0;
    char* w = (char*)d_ws;
    auto take = [&](size_t bytes) -> void* {
        void* p = w + off;
        off = (off + bytes + 255) & ~(size_t)255;
        return p;
    };

    u16* pwg     = (u16*)take((size_t)3 * HF * HF * 2);
    u16* pwe1    = (u16*)take((size_t)3 * HF * EF * 2);
    u16* pwe2    = (u16*)take((size_t)3 * EF * HF * 2);
    u16* pwp     = (u16*)take((size_t)HF * HF * 2);
    u16* pf1     = (u16*)take((size_t)HF * HF * 2);
    u16* pf2     = (u16*)take((size_t)HF * HF * 2);
    int* counts  = (int*)take((size_t)NNODES * 4);
    int* row_ptr = (int*)take((size_t)NNODES * 4);
    int* cursor  = (int*)take((size_t)NNODES * 4);
    int* es      = (int*)take((size_t)NEDGES * 4);
    int* bsums   = (int*)take(2048);
    int* boffs   = (int*)take(2048);
    float* xsum  = (float*)take((size_t)NGRAPHS * HF * 4);
    u16* x       = (u16*)take((size_t)NNODES * HF * 2);
    u16* M       = (u16*)take((size_t)NNODES * HF * 2);

    hipMemsetAsync(counts, 0, (size_t)NNODES * 4, stream);

    // prep: conv repack (960) + head repack (192) + count (2344) + xsum zero (64)
    prep_kernel<<<3560, 256, 0, stream>>>(d_in[6], d_in[7], d_in[8],
                                          d_in[9], d_in[10], d_in[12],
                                          pwg, pwe1, pwe2, pwp, pf1, pf2,
                                          d_in[5], etgt, counts, xsum);

    const int NB_SCAN = (NNODES + 255) / 256;      // 391
    const int NB_EDGE = (NEDGES + 255) / 256;      // 2344
    scan1_kernel<<<NB_SCAN, 256, 0, stream>>>(counts, row_ptr, bsums);
    scan2_kernel<<<1, 512, 0, stream>>>(bsums, boffs, NB_SCAN);
    scan3_kernel<<<NB_SCAN, 256, 0, stream>>>(row_ptr, boffs, cursor);
    fill_kernel<<<NB_EDGE, 256, 0, stream>>>(esrc, etgt, cursor, es);

    const int NBC = (NNODES + 31) / 32;            // 3125
    const int NBA = (NNODES + 15) / 16;            // 6250
    conv0_mfma<<<NBC, 256, 0, stream>>>(nodes, d_in[5], x, pwg, pwe1, pwe2, M);
    agg_kernel<<<NBA, 256, 0, stream>>>(M, row_ptr, counts, es, x);
    conv_mfma<<<NBC, 256, 0, stream>>>(x,
        pwg + (size_t)1 * HF * HF, pwe1 + (size_t)1 * HF * EF, pwe2 + (size_t)1 * EF * HF, M);
    agg_kernel<<<NBA, 256, 0, stream>>>(M, row_ptr, counts, es, x);
    conv_mfma<<<NBC, 256, 0, stream>>>(x,
        pwg + (size_t)2 * HF * HF, pwe1 + (size_t)2 * HF * EF, pwe2 + (size_t)2 * EF * HF, M);
    agg_kernel<<<NBA, 256, 0, stream>>>(M, row_ptr, counts, es, x);

    pool_kernel<<<(NNODES + 255) / 256, 256, 0, stream>>>(x, gidx, xsum);
    head_mfma<<<NGRAPHS / GB, 256, 0, stream>>>(xsum, d_in[4], pwp, pf1, pf2,
                                                d_in[11], d_in[13], d_in[14], d_in[15],
                                                d_out, d_in[5]);
}

// Round 3
// 390.419 us; speedup vs baseline: 1.0188x; 1.0056x over previous
//
#include <hip/hip_runtime.h>
#include <hip/hip_bf16.h>

typedef unsigned short u16;
typedef __attribute__((ext_vector_type(8))) short short8;
typedef __attribute__((ext_vector_type(4))) float f32x4;
typedef __attribute__((ext_vector_type(16))) float f32x16;
typedef __attribute__((ext_vector_type(2))) __bf16 bf16x2;

#define NNODES 100000
#define NEDGES 600000
#define NGRAPHS 512
#define HF 128
#define EF 256
#define GB 32       // graphs per head block

// chunk-major LDS planes, 32-node tiles: plane = 32 rows x 16B + 16B pad
// -> stride 264 u16 (528 B = 132 dwords == 4 banks mod 32)
#define PLD 264
__device__ __forceinline__ int cidx(int chunk, int row){ return chunk * PLD + row * 8; }

__device__ __forceinline__ float bfu(u16 u){ return __uint_as_float(((unsigned)u) << 16); }
__device__ __forceinline__ u16 f2bf(float f){
    unsigned u = __float_as_uint(f);
    unsigned r = (u + 0x7fff + ((u >> 16) & 1)) >> 16;
    return (u16)r;
}
// HW packed f32->bf16 RNE (v_cvt_pk_bf16_f32 on gfx950)
__device__ __forceinline__ unsigned pack2(float a, float b){
    bf16x2 v = { (__bf16)a, (__bf16)b };
    return __builtin_bit_cast(unsigned, v);
}

#if __has_builtin(__builtin_amdgcn_rcpf)
#define RCP1(x) __builtin_amdgcn_rcpf(x)
#else
#define RCP1(x) (1.f / (x))
#endif

// cheap softplus: log(1+exp(x)) direct — safe for |x| << 80 (values here <~20)
__device__ __forceinline__ float sp_f(float x){
    return __logf(1.f + __expf(x));
}
__device__ __forceinline__ float sig_f(float x){
    return RCP1(1.f + __expf(-x));
}
__device__ __forceinline__ float lf(const void* p, long i, bool f32){
    return f32 ? ((const float*)p)[i] : bfu(((const u16*)p)[i]);
}

// in-register dtype detection: probe 256 u16 of the embed table as bf16
__device__ __forceinline__ bool is_f32(const void* probe){
    const u16* p = (const u16*)probe;
    int lane = threadIdx.x & 63;
    int c = 0;
#pragma unroll
    for (int i = 0; i < 4; i++) c += (fabsf(bfu(p[lane * 4 + i])) > 1.0f) ? 1 : 0;
#pragma unroll
    for (int off = 32; off; off >>= 1) c += __shfl_xor(c, off, 64);
    return c > 8;
}

// ---------------- prep: weight repack + edge count + xsum zero ----------------
// conv weights -> 32x32x16 A-frag order: P[ks][nt32][lane][8]; lane l holds
//   W[k = ks*16 + (l>>5)*8 + j][n = nt32*32 + (l&31)], j=0..7  (W^T as A operand)
// head weights -> 16x16x32 frag order.
// blocks [0,960): conv; [960,1152): head; [1152,3496): edge count;
// [3496,3560): zero xsum (64 blocks x 256 x float4)
__global__ __launch_bounds__(256) void prep_kernel(const void* __restrict__ wg,
                                                   const void* __restrict__ we1,
                                                   const void* __restrict__ we2,
                                                   const void* __restrict__ wp,
                                                   const void* __restrict__ wfc1,
                                                   const void* __restrict__ wfc2,
                                                   u16* __restrict__ pwg,
                                                   u16* __restrict__ pwe1,
                                                   u16* __restrict__ pwe2,
                                                   u16* __restrict__ pwp,
                                                   u16* __restrict__ pf1,
                                                   u16* __restrict__ pf2,
                                                   const void* __restrict__ emb,
                                                   const int* __restrict__ tgt,
                                                   int* __restrict__ counts,
                                                   float* __restrict__ xsum){
    int b = blockIdx.x, t = threadIdx.x;
    if (b < 960) {
        bool f32 = is_f32(emb);
        int i = b * 256 + t;                       // < 3*81920
        int c = i / 81920, r = i % 81920;
        const void* src; u16* dst; int N, KN, l;
        if (r < 16384)      { src = wg;  dst = pwg;  N = HF; KN = 16384; l = r; }
        else if (r < 49152) { src = we1; dst = pwe1; N = EF; KN = 32768; l = r - 16384; }
        else                { src = we2; dst = pwe2; N = HF; KN = 32768; l = r - 49152; }
        int j = l & 7, lane = (l >> 3) & 63, rest = l >> 9;
        int NT = N >> 5;
        int nt = rest % NT, ks = rest / NT;
        int k = ks * 16 + (lane >> 5) * 8 + j;
        int n = nt * 32 + (lane & 31);
        long base = (long)c * KN;
        dst[base + l] = f2bf(lf(src, base + (long)k * N + n, f32));
    } else if (b < 1152) {
        bool f32 = is_f32(emb);
        int i = (b - 960) * 256 + t;               // < 3*16384
        int c = i / 16384, l = i % 16384;
        const void* src = (c == 0) ? wp : (c == 1) ? wfc1 : wfc2;
        u16* dst = (c == 0) ? pwp : (c == 1) ? pf1 : pf2;
        int j = l & 7, lane = (l >> 3) & 63, rest = l >> 9;
        int nt = rest & 7, kt = rest >> 3;         // 16x16 layout, N=128
        int k = kt * 32 + (lane >> 4) * 8 + j;
        int n = nt * 16 + (lane & 15);
        dst[l] = f2bf(lf(src, (long)k * HF + n, f32));
    } else if (b < 3496) {
        int e = (b - 1152) * 256 + t;
        if (e < NEDGES) atomicAdd(&counts[tgt[e]], 1);
    } else {
        int i = (b - 3496) * 256 + t;              // < 16384 float4s
        ((float4*)xsum)[i] = make_float4(0.f, 0.f, 0.f, 0.f);
    }
}

// ---------------- CSR build ----------------
__global__ __launch_bounds__(256) void scan1_kernel(const int* __restrict__ counts,
                                                    int* __restrict__ row_ptr,
                                                    int* __restrict__ bsums){
    __shared__ int s[256];
    int t = threadIdx.x;
    int i = blockIdx.x * 256 + t;
    int v = (i < NNODES) ? counts[i] : 0;
    s[t] = v; __syncthreads();
    for (int off = 1; off < 256; off <<= 1) {
        int a = (t >= off) ? s[t - off] : 0;
        __syncthreads();
        s[t] += a;
        __syncthreads();
    }
    if (i < NNODES) row_ptr[i] = s[t] - v;
    if (t == 255) bsums[blockIdx.x] = s[255];
}

__global__ __launch_bounds__(512) void scan2_kernel(const int* __restrict__ bsums,
                                                    int* __restrict__ boffs, int nb){
    __shared__ int s[512];
    int t = threadIdx.x;
    int v = (t < nb) ? bsums[t] : 0;
    s[t] = v; __syncthreads();
    for (int off = 1; off < 512; off <<= 1) {
        int a = (t >= off) ? s[t - off] : 0;
        __syncthreads();
        s[t] += a;
        __syncthreads();
    }
    if (t < nb) boffs[t] = s[t] - v;
}

__global__ __launch_bounds__(256) void scan3_kernel(int* __restrict__ row_ptr,
                                                    const int* __restrict__ boffs,
                                                    int* __restrict__ cursor){
    int i = blockIdx.x * 256 + threadIdx.x;
    if (i < NNODES) {
        int r = row_ptr[i] + boffs[blockIdx.x];
        row_ptr[i] = r;
        cursor[i]  = r;
    }
}

__global__ __launch_bounds__(256) void fill_kernel(const int* __restrict__ src,
                                                   const int* __restrict__ tgt,
                                                   int* __restrict__ cursor,
                                                   int* __restrict__ es){
    int e = blockIdx.x * 256 + threadIdx.x;
    if (e < NEDGES) {
        int pos = atomicAdd(&cursor[tgt[e]], 1);
        es[pos] = src[e];
    }
}

// ========== conv MFMA phases, 32x32x16, 32-node tile, FULL U in LDS ==========
// Software-pipelined: every A-fragment stream (We1 x2, Wg, We2) is prefetched
// 1 step ahead so the L2 load latency hides under the previous MFMA. G phase
// runs BEFORE the barrier (only needs xs) so waves arrive staggered.
// LDS: xs 8.45 KB + us 16.9 KB = 25.3 KB. __launch_bounds__(256,4) -> 128
// VGPR cap: acc pair (32) + prefetch frags (32) + B (8) fit with headroom.
// Accumulation order per accumulator is bit-identical to previous version.
__device__ __forceinline__ void conv_phases(u16* xs, u16* us,
                                            const u16* __restrict__ pwg,
                                            const u16* __restrict__ pwe1,
                                            const u16* __restrict__ pwe2,
                                            u16* __restrict__ M, long row0){
    const int t = threadIdx.x;
    const int w = t >> 6, lane = t & 63;
    const int half = lane >> 5, nn = lane & 31;

    // ---- U phase: wave w owns ef-tiles et = w and et = w+4 ----
    // pwe1 index: ((ks*8 + et)*64 + lane)*8 -> ks stride 4096 u16, et stride 512
    const u16* pA0 = pwe1 + ((w * 64 + lane) << 3);
    const u16* pA1 = pwe1 + (((w + 4) * 64 + lane) << 3);
    short8 a0 = *(const short8*)(pA0);
    short8 a1 = *(const short8*)(pA1);
    f32x16 acc0 = {}, acc1 = {};
#pragma unroll
    for (int ks = 0; ks < 8; ks++) {
        short8 n0, n1;
        if (ks < 7) {
            n0 = *(const short8*)(pA0 + (ks + 1) * 4096);
            n1 = *(const short8*)(pA1 + (ks + 1) * 4096);
        }
        short8 B = *(const short8*)(&xs[cidx(ks * 2 + half, nn)]);
        acc0 = __builtin_amdgcn_mfma_f32_32x32x16_bf16(a0, B, acc0, 0, 0, 0);
        acc1 = __builtin_amdgcn_mfma_f32_32x32x16_bf16(a1, B, acc1, 0, 0, 0);
        a0 = n0; a1 = n1;
    }
#pragma unroll
    for (int q = 0; q < 4; q++) {
        uint2 d;
        d.x = pack2(sp_f(acc0[q*4+0]), sp_f(acc0[q*4+1]));
        d.y = pack2(sp_f(acc0[q*4+2]), sp_f(acc0[q*4+3]));
        *(uint2*)(&us[cidx(w * 4 + q, nn) + half * 4]) = d;
        uint2 e;
        e.x = pack2(sp_f(acc1[q*4+0]), sp_f(acc1[q*4+1]));
        e.y = pack2(sp_f(acc1[q*4+2]), sp_f(acc1[q*4+3]));
        *(uint2*)(&us[cidx(16 + w * 4 + q, nn) + half * 4]) = e;
    }

    // ---- G phase (pre-barrier; only reads xs): aG = Wg^T[h-tile w] @ x^T ----
    // pwg index: ((ks*4 + w)*64 + lane)*8 -> ks stride 2048 u16
    const u16* pAg = pwg + ((w * 64 + lane) << 3);
    short8 ag = *(const short8*)(pAg);
    f32x16 aG = {};
#pragma unroll
    for (int ks = 0; ks < 8; ks++) {
        short8 ng;
        if (ks < 7) ng = *(const short8*)(pAg + (ks + 1) * 2048);
        short8 B = *(const short8*)(&xs[cidx(ks * 2 + half, nn)]);
        aG = __builtin_amdgcn_mfma_f32_32x32x16_bf16(ag, B, aG, 0, 0, 0);
        ag = ng;
    }
    __syncthreads();

    // ---- C phase: aT = We2^T[h-tile w] @ U, K=256 in 16 steps ----
    // pwe2 index: ((jj*4 + w)*64 + lane)*8 -> jj stride 2048 u16
    const u16* pAc = pwe2 + ((w * 64 + lane) << 3);
    short8 ac = *(const short8*)(pAc);
    f32x16 aT = {};
#pragma unroll
    for (int jj = 0; jj < 16; jj++) {
        short8 nc;
        if (jj < 15) nc = *(const short8*)(pAc + (jj + 1) * 2048);
        short8 B = *(const short8*)(&us[cidx(jj * 2 + half, nn)]);
        aT = __builtin_amdgcn_mfma_f32_32x32x16_bf16(ac, B, aT, 0, 0, 0);
        ac = nc;
    }

    // ---- combine gate + message, write M ----
    long node = row0 + nn;                         // 3125*32 == NNODES exactly
#pragma unroll
    for (int q = 0; q < 4; q++) {
        int h0 = w * 32 + half * 4 + q * 8;
        uint2 d;
        d.x = pack2(sig_f(aG[q*4+0]) * sp_f(aT[q*4+0]),
                    sig_f(aG[q*4+1]) * sp_f(aT[q*4+1]));
        d.y = pack2(sig_f(aG[q*4+2]) * sp_f(aT[q*4+2]),
                    sig_f(aG[q*4+3]) * sp_f(aT[q*4+3]));
        *(uint2*)(M + node * HF + h0) = d;
    }
}

// ---------------- conv0: embed fused (vectorized uint4); writes x and M ----------------
__global__ __launch_bounds__(256, 4) void conv0_mfma(const int* __restrict__ nodes,
                                                     const void* __restrict__ emb,
                                                     u16* __restrict__ x,
                                                     const u16* __restrict__ pwg,
                                                     const u16* __restrict__ pwe1,
                                                     const u16* __restrict__ pwe2,
                                                     u16* __restrict__ M){
    __shared__ u16 xs[16 * PLD];   //  8,448 B
    __shared__ u16 us[32 * PLD];   // 16,896 B
    const int t = threadIdx.x;
    const long row0 = (long)blockIdx.x * 32;
    const bool f32 = is_f32(emb);

    for (int i = t; i < 512; i += 256) {           // (row r, chunk q): 16B each
        int r = i >> 4, q = i & 15;
        long node = row0 + r;                      // always < NNODES (exact fit)
        int v = nodes[node];
        uint4 d;
        if (f32) {
            float4 f0 = ((const float4*)emb)[(long)v * 32 + q * 2];
            float4 f1 = ((const float4*)emb)[(long)v * 32 + q * 2 + 1];
            d.x = pack2(f0.x, f0.y); d.y = pack2(f0.z, f0.w);
            d.z = pack2(f1.x, f1.y); d.w = pack2(f1.z, f1.w);
        } else {
            d = ((const uint4*)emb)[(long)v * 16 + q];
        }
        ((uint4*)x)[node * 16 + q] = d;
        *(uint4*)(&xs[cidx(q, r)]) = d;
    }
    __syncthreads();
    conv_phases(xs, us, pwg, pwe1, pwe2, M, row0);
}

// ---------------- conv: stages x from global; writes M ----------------
__global__ __launch_bounds__(256, 4) void conv_mfma(const u16* __restrict__ x,
                                                    const u16* __restrict__ pwg,
                                                    const u16* __restrict__ pwe1,
                                                    const u16* __restrict__ pwe2,
                                                    u16* __restrict__ M){
    __shared__ u16 xs[16 * PLD];
    __shared__ u16 us[32 * PLD];
    const int t = threadIdx.x;
    const long row0 = (long)blockIdx.x * 32;

    for (int i = t; i < 512; i += 256) {
        int r = i >> 4, q = i & 15;
        long node = row0 + r;                      // always < NNODES (exact fit)
        uint4 v = ((const uint4*)x)[node * 16 + q];
        *(uint4*)(&xs[cidx(q, r)]) = v;
    }
    __syncthreads();
    conv_phases(xs, us, pwg, pwe1, pwe2, M, row0);
}

// ---------------- aggregation: x[v] += sp( sum_{e: tgt=v} M[src[e]] ) ----------------
// uint4 per lane, 16 lanes per node row, 4 nodes per wave, 4x-unrolled gather.
__global__ __launch_bounds__(256) void agg_kernel(const u16* __restrict__ M,
                                                  const int* __restrict__ row_ptr,
                                                  const int* __restrict__ counts,
                                                  const int* __restrict__ es,
                                                  u16* __restrict__ x){
    int wid = blockIdx.x * 4 + (threadIdx.x >> 6);
    int lane = threadIdx.x & 63;
    long v = (long)wid * 4 + (lane >> 4);
    int l = lane & 15;
    if (v >= NNODES) return;
    int start = row_ptr[v], cnt = counts[v];
    float a0=0.f,a1=0.f,a2=0.f,a3=0.f,a4=0.f,a5=0.f,a6=0.f,a7=0.f;
    float b0=0.f,b1=0.f,b2=0.f,b3=0.f,b4=0.f,b5=0.f,b6=0.f,b7=0.f;
    const uint4* Mu = (const uint4*)M;
    int e = 0;
    for (; e + 3 < cnt; e += 4) {
        int s0 = es[start + e],     s1 = es[start + e + 1];
        int s2 = es[start + e + 2], s3 = es[start + e + 3];
        uint4 u0 = Mu[(long)s0 * 16 + l];
        uint4 u1 = Mu[(long)s1 * 16 + l];
        uint4 u2 = Mu[(long)s2 * 16 + l];
        uint4 u3 = Mu[(long)s3 * 16 + l];
        a0 += bfu((u16)u0.x); a1 += bfu((u16)(u0.x >> 16));
        a2 += bfu((u16)u0.y); a3 += bfu((u16)(u0.y >> 16));
        a4 += bfu((u16)u0.z); a5 += bfu((u16)(u0.z >> 16));
        a6 += bfu((u16)u0.w); a7 += bfu((u16)(u0.w >> 16));
        b0 += bfu((u16)u1.x); b1 += bfu((u16)(u1.x >> 16));
        b2 += bfu((u16)u1.y); b3 += bfu((u16)(u1.y >> 16));
        b4 += bfu((u16)u1.z); b5 += bfu((u16)(u1.z >> 16));
        b6 += bfu((u16)u1.w); b7 += bfu((u16)(u1.w >> 16));
        a0 += bfu((u16)u2.x); a1 += bfu((u16)(u2.x >> 16));
        a2 += bfu((u16)u2.y); a3 += bfu((u16)(u2.y >> 16));
        a4 += bfu((u16)u2.z); a5 += bfu((u16)(u2.z >> 16));
        a6 += bfu((u16)u2.w); a7 += bfu((u16)(u2.w >> 16));
        b0 += bfu((u16)u3.x); b1 += bfu((u16)(u3.x >> 16));
        b2 += bfu((u16)u3.y); b3 += bfu((u16)(u3.y >> 16));
        b4 += bfu((u16)u3.z); b5 += bfu((u16)(u3.z >> 16));
        b6 += bfu((u16)u3.w); b7 += bfu((u16)(u3.w >> 16));
    }
    for (; e < cnt; e++) {
        int s0 = es[start + e];
        uint4 u0 = Mu[(long)s0 * 16 + l];
        a0 += bfu((u16)u0.x); a1 += bfu((u16)(u0.x >> 16));
        a2 += bfu((u16)u0.y); a3 += bfu((u16)(u0.y >> 16));
        a4 += bfu((u16)u0.z); a5 += bfu((u16)(u0.z >> 16));
        a6 += bfu((u16)u0.w); a7 += bfu((u16)(u0.w >> 16));
    }
    a0 += b0; a1 += b1; a2 += b2; a3 += b3;
    a4 += b4; a5 += b5; a6 += b6; a7 += b7;
    uint4* xu = (uint4*)x;
    uint4 xv = xu[v * 16 + l];
    xv.x = pack2(bfu((u16)xv.x) + sp_f(a0), bfu((u16)(xv.x >> 16)) + sp_f(a1));
    xv.y = pack2(bfu((u16)xv.y) + sp_f(a2), bfu((u16)(xv.y >> 16)) + sp_f(a3));
    xv.z = pack2(bfu((u16)xv.z) + sp_f(a4), bfu((u16)(xv.z >> 16)) + sp_f(a5));
    xv.w = pack2(bfu((u16)xv.w) + sp_f(a6), bfu((u16)(xv.w >> 16)) + sp_f(a7));
    xu[v * 16 + l] = xv;
}

// ---------------- pooling: xsum[g] = sum of x rows of graph g (atomic flush) ----------------
__global__ __launch_bounds__(256) void pool_kernel(const u16* __restrict__ x,
                                                   const int* __restrict__ gidx,
                                                   float* __restrict__ xsum){
    int wave = blockIdx.x * 4 + (threadIdx.x >> 6);
    int lane = threadIdx.x & 63;
    long base = (long)wave * 64;
    if (base >= NNODES) return;
    long end = base + 64; if (end > NNODES) end = NNODES;
    const unsigned* xu = (const unsigned*)x;
    int gcur = gidx[base];
    float a0 = 0.f, a1 = 0.f;
    for (long v = base; v < end; v++) {
        int g = gidx[v];                           // wave-uniform
        if (g != gcur) {
            atomicAdd(&xsum[gcur * HF + lane * 2 + 0], a0);
            atomicAdd(&xsum[gcur * HF + lane * 2 + 1], a1);
            a0 = a1 = 0.f; gcur = g;
        }
        unsigned u = xu[v * 64 + lane];
        a0 += bfu((u16)u);
        a1 += bfu((u16)(u >> 16));
    }
    atomicAdd(&xsum[gcur * HF + lane * 2 + 0], a0);
    atomicAdd(&xsum[gcur * HF + lane * 2 + 1], a1);
}

// ---------------- head via transposed 16x16 MFMA, bf16 hi+lo activations ----------------
__global__ __launch_bounds__(256) void head_mfma(const float* __restrict__ xsum,
                                                 const void* __restrict__ ncnt,
                                                 const u16* __restrict__ pwp,
                                                 const u16* __restrict__ pf1,
                                                 const u16* __restrict__ pf2,
                                                 const void* __restrict__ bfc1,
                                                 const void* __restrict__ bfc2,
                                                 const void* __restrict__ Wr,
                                                 const void* __restrict__ br,
                                                 void* __restrict__ out,
                                                 const void* __restrict__ probe){
    __shared__ u16 hibuf[2][GB][136];
    __shared__ u16 lobuf[2][GB][136];
    const int t = threadIdx.x;
    const int w = t >> 6, lane = t & 63;
    const int quad = lane >> 4, nr = lane & 15;
    const bool f32 = is_f32(probe);
    const int g0 = blockIdx.x * GB;

    for (int i = t; i < GB * 64; i += 256) {
        int g = i >> 6, c = (i & 63) * 2;
        float f0 = xsum[(g0 + g) * HF + c], f1 = xsum[(g0 + g) * HF + c + 1];
        u16 h0 = f2bf(f0), h1 = f2bf(f1);
        *(unsigned*)&hibuf[0][g][c] = (unsigned)h0 | ((unsigned)h1 << 16);
        *(unsigned*)&lobuf[0][g][c] = pack2(f0 - bfu(h0), f1 - bfu(h1));
    }
    __syncthreads();

    float rc[2];
#pragma unroll
    for (int nt = 0; nt < 2; nt++) rc[nt] = RCP1(lf(ncnt, g0 + nt * 16 + nr, f32));

    int cur = 0;
    for (int layer = 0; layer < 3; layer++) {
        const u16* pw = (layer == 0) ? pwp : (layer == 1) ? pf1 : pf2;
        const void* bias = (layer == 1) ? bfc1 : bfc2;
        int nxt = cur ^ 1;
#pragma unroll
        for (int c = 0; c < 2; c++) {
            int et = w * 2 + c;
            short8 A[4];
#pragma unroll
            for (int kt = 0; kt < 4; kt++)
                A[kt] = *(const short8*)(pw + (((kt * 8 + et) * 64 + lane) << 3));
#pragma unroll
            for (int nt = 0; nt < 2; nt++) {
                f32x4 acc = {0.f, 0.f, 0.f, 0.f};
#pragma unroll
                for (int kt = 0; kt < 4; kt++) {
                    short8 bh = *(const short8*)(&hibuf[cur][nt * 16 + nr][kt * 32 + quad * 8]);
                    short8 bl = *(const short8*)(&lobuf[cur][nt * 16 + nr][kt * 32 + quad * 8]);
                    acc = __builtin_amdgcn_mfma_f32_16x16x32_bf16(A[kt], bh, acc, 0, 0, 0);
                    acc = __builtin_amdgcn_mfma_f32_16x16x32_bf16(A[kt], bl, acc, 0, 0, 0);
                }
                int feat0 = et * 16 + quad * 4;
                float f[4];
#pragma unroll
                for (int r = 0; r < 4; r++) {
                    float a = (layer == 0) ? acc[r] * rc[nt]
                                           : acc[r] + lf(bias, feat0 + r, f32);
                    f[r] = sp_f(a);
                }
                u16 h[4]; float lo[4];
#pragma unroll
                for (int r = 0; r < 4; r++) { h[r] = f2bf(f[r]); lo[r] = f[r] - bfu(h[r]); }
                uint2 dh, dl;
                dh.x = (unsigned)h[0] | ((unsigned)h[1] << 16);
                dh.y = (unsigned)h[2] | ((unsigned)h[3] << 16);
                dl.x = pack2(lo[0], lo[1]);
                dl.y = pack2(lo[2], lo[3]);
                *(uint2*)&hibuf[nxt][nt * 16 + nr][feat0] = dh;
                *(uint2*)&lobuf[nxt][nt * 16 + nr][feat0] = dl;
            }
        }
        __syncthreads();
        cur = nxt;
    }

    int g = t >> 3, sub = t & 7;
    float p = 0.f;
    for (int k = sub * 16; k < sub * 16 + 16; k++) {
        float v = bfu(hibuf[cur][g][k]) + bfu(lobuf[cur][g][k]);
        p += v * lf(Wr, k, f32);
    }
    p += __shfl_down(p, 4, 64);
    p += __shfl_down(p, 2, 64);
    p += __shfl_down(p, 1, 64);
    if (sub == 0) {
        float res = p + lf(br, 0, f32);
        if (f32) ((float*)out)[g0 + g] = res;
        else     ((u16*)out)[g0 + g]  = f2bf(res);
    }
}

extern "C" void kernel_launch(void* const* d_in, const int* in_sizes, int n_in,
                              void* d_out, int out_size, void* d_ws, size_t ws_size,
                              hipStream_t stream) {
    const int* nodes = (const int*)d_in[0];
    const int* esrc  = (const int*)d_in[1];
    const int* etgt  = (const int*)d_in[2];
    const int* gidx  = (const int*)d_in[3];

    size_t off = 0;
    char* w = (char*)d_ws;
    auto take = [&](size_t bytes) -> void* {
        void* p = w + off;
        off = (off + bytes + 255) & ~(size_t)255;
        return p;
    };

    u16* pwg     = (u16*)take((size_t)3 * HF * HF * 2);
    u16* pwe1    = (u16*)take((size_t)3 * HF * EF * 2);
    u16* pwe2    = (u16*)take((size_t)3 * EF * HF * 2);
    u16* pwp     = (u16*)take((size_t)HF * HF * 2);
    u16* pf1     = (u16*)take((size_t)HF * HF * 2);
    u16* pf2     = (u16*)take((size_t)HF * HF * 2);
    int* counts  = (int*)take((size_t)NNODES * 4);
    int* row_ptr = (int*)take((size_t)NNODES * 4);
    int* cursor  = (int*)take((size_t)NNODES * 4);
    int* es      = (int*)take((size_t)NEDGES * 4);
    int* bsums   = (int*)take(2048);
    int* boffs   = (int*)take(2048);
    float* xsum  = (float*)take((size_t)NGRAPHS * HF * 4);
    u16* x       = (u16*)take((size_t)NNODES * HF * 2);
    u16* M       = (u16*)take((size_t)NNODES * HF * 2);

    hipMemsetAsync(counts, 0, (size_t)NNODES * 4, stream);

    // prep: conv repack (960) + head repack (192) + count (2344) + xsum zero (64)
    prep_kernel<<<3560, 256, 0, stream>>>(d_in[6], d_in[7], d_in[8],
                                          d_in[9], d_in[10], d_in[12],
                                          pwg, pwe1, pwe2, pwp, pf1, pf2,
                                          d_in[5], etgt, counts, xsum);

    const int NB_SCAN = (NNODES + 255) / 256;      // 391
    const int NB_EDGE = (NEDGES + 255) / 256;      // 2344
    scan1_kernel<<<NB_SCAN, 256, 0, stream>>>(counts, row_ptr, bsums);
    scan2_kernel<<<1, 512, 0, stream>>>(bsums, boffs, NB_SCAN);
    scan3_kernel<<<NB_SCAN, 256, 0, stream>>>(row_ptr, boffs, cursor);
    fill_kernel<<<NB_EDGE, 256, 0, stream>>>(esrc, etgt, cursor, es);

    const int NBC = (NNODES + 31) / 32;            // 3125
    const int NBA = (NNODES + 15) / 16;            // 6250
    conv0_mfma<<<NBC, 256, 0, stream>>>(nodes, d_in[5], x, pwg, pwe1, pwe2, M);
    agg_kernel<<<NBA, 256, 0, stream>>>(M, row_ptr, counts, es, x);
    conv_mfma<<<NBC, 256, 0, stream>>>(x,
        pwg + (size_t)1 * HF * HF, pwe1 + (size_t)1 * HF * EF, pwe2 + (size_t)1 * EF * HF, M);
    agg_kernel<<<NBA, 256, 0, stream>>>(M, row_ptr, counts, es, x);
    conv_mfma<<<NBC, 256, 0, stream>>>(x,
        pwg + (size_t)2 * HF * HF, pwe1 + (size_t)2 * HF * EF, pwe2 + (size_t)2 * EF * HF, M);
    agg_kernel<<<NBA, 256, 0, stream>>>(M, row_ptr, counts, es, x);

    pool_kernel<<<(NNODES + 255) / 256, 256, 0, stream>>>(x, gidx, xsum);
    head_mfma<<<NGRAPHS / GB, 256, 0, stream>>>(xsum, d_in[4], pwp, pf1, pf2,
                                                d_in[11], d_in[13], d_in[14], d_in[15],
                                                d_out, d_in[5]);
}

// Round 4
// 387.998 us; speedup vs baseline: 1.0252x; 1.0062x over previous
//
#include <hip/hip_runtime.h>
#include <hip/hip_bf16.h>

typedef unsigned short u16;
typedef __attribute__((ext_vector_type(8))) short short8;
typedef __attribute__((ext_vector_type(4))) float f32x4;
typedef __attribute__((ext_vector_type(16))) float f32x16;
typedef __attribute__((ext_vector_type(2))) __bf16 bf16x2;

#define NNODES 100000
#define NEDGES 600000
#define NGRAPHS 512
#define HF 128
#define EF 256
#define GB 32       // graphs per head block
#define NTILES 3125 // 100000 / 32
#define GRID_CONV 512

// chunk-major LDS planes, 32-node tiles: plane = 32 rows x 16B + 16B pad
// -> stride 264 u16 (528 B = 132 dwords == 4 banks mod 32)
#define PLD 264
__device__ __forceinline__ int cidx(int chunk, int row){ return chunk * PLD + row * 8; }

__device__ __forceinline__ float bfu(u16 u){ return __uint_as_float(((unsigned)u) << 16); }
__device__ __forceinline__ u16 f2bf(float f){
    unsigned u = __float_as_uint(f);
    unsigned r = (u + 0x7fff + ((u >> 16) & 1)) >> 16;
    return (u16)r;
}
// HW packed f32->bf16 RNE (v_cvt_pk_bf16_f32 on gfx950)
__device__ __forceinline__ unsigned pack2(float a, float b){
    bf16x2 v = { (__bf16)a, (__bf16)b };
    return __builtin_bit_cast(unsigned, v);
}

#if __has_builtin(__builtin_amdgcn_rcpf)
#define RCP1(x) __builtin_amdgcn_rcpf(x)
#else
#define RCP1(x) (1.f / (x))
#endif

// cheap softplus: log(1+exp(x)) direct — safe for |x| << 80 (values here <~20)
__device__ __forceinline__ float sp_f(float x){
    return __logf(1.f + __expf(x));
}
__device__ __forceinline__ float sig_f(float x){
    return RCP1(1.f + __expf(-x));
}
__device__ __forceinline__ float lf(const void* p, long i, bool f32){
    return f32 ? ((const float*)p)[i] : bfu(((const u16*)p)[i]);
}

// in-register dtype detection: probe 256 u16 of the embed table as bf16
__device__ __forceinline__ bool is_f32(const void* probe){
    const u16* p = (const u16*)probe;
    int lane = threadIdx.x & 63;
    int c = 0;
#pragma unroll
    for (int i = 0; i < 4; i++) c += (fabsf(bfu(p[lane * 4 + i])) > 1.0f) ? 1 : 0;
#pragma unroll
    for (int off = 32; off; off >>= 1) c += __shfl_xor(c, off, 64);
    return c > 8;
}

// ---------------- prep: weight repack + edge count + xsum zero ----------------
// conv weights -> 32x32x16 A-frag order: P[ks][nt32][lane][8]; lane l holds
//   W[k = ks*16 + (l>>5)*8 + j][n = nt32*32 + (l&31)], j=0..7  (W^T as A operand)
// head weights -> 16x16x32 frag order.
// blocks [0,960): conv; [960,1152): head; [1152,3496): edge count;
// [3496,3560): zero xsum (64 blocks x 256 x float4)
__global__ __launch_bounds__(256) void prep_kernel(const void* __restrict__ wg,
                                                   const void* __restrict__ we1,
                                                   const void* __restrict__ we2,
                                                   const void* __restrict__ wp,
                                                   const void* __restrict__ wfc1,
                                                   const void* __restrict__ wfc2,
                                                   u16* __restrict__ pwg,
                                                   u16* __restrict__ pwe1,
                                                   u16* __restrict__ pwe2,
                                                   u16* __restrict__ pwp,
                                                   u16* __restrict__ pf1,
                                                   u16* __restrict__ pf2,
                                                   const void* __restrict__ emb,
                                                   const int* __restrict__ tgt,
                                                   int* __restrict__ counts,
                                                   float* __restrict__ xsum){
    int b = blockIdx.x, t = threadIdx.x;
    if (b < 960) {
        bool f32 = is_f32(emb);
        int i = b * 256 + t;                       // < 3*81920
        int c = i / 81920, r = i % 81920;
        const void* src; u16* dst; int N, KN, l;
        if (r < 16384)      { src = wg;  dst = pwg;  N = HF; KN = 16384; l = r; }
        else if (r < 49152) { src = we1; dst = pwe1; N = EF; KN = 32768; l = r - 16384; }
        else                { src = we2; dst = pwe2; N = HF; KN = 32768; l = r - 49152; }
        int j = l & 7, lane = (l >> 3) & 63, rest = l >> 9;
        int NT = N >> 5;
        int nt = rest % NT, ks = rest / NT;
        int k = ks * 16 + (lane >> 5) * 8 + j;
        int n = nt * 32 + (lane & 31);
        long base = (long)c * KN;
        dst[base + l] = f2bf(lf(src, base + (long)k * N + n, f32));
    } else if (b < 1152) {
        bool f32 = is_f32(emb);
        int i = (b - 960) * 256 + t;               // < 3*16384
        int c = i / 16384, l = i % 16384;
        const void* src = (c == 0) ? wp : (c == 1) ? wfc1 : wfc2;
        u16* dst = (c == 0) ? pwp : (c == 1) ? pf1 : pf2;
        int j = l & 7, lane = (l >> 3) & 63, rest = l >> 9;
        int nt = rest & 7, kt = rest >> 3;         // 16x16 layout, N=128
        int k = kt * 32 + (lane >> 4) * 8 + j;
        int n = nt * 16 + (lane & 15);
        dst[l] = f2bf(lf(src, (long)k * HF + n, f32));
    } else if (b < 3496) {
        int e = (b - 1152) * 256 + t;
        if (e < NEDGES) atomicAdd(&counts[tgt[e]], 1);
    } else {
        int i = (b - 3496) * 256 + t;              // < 16384 float4s
        ((float4*)xsum)[i] = make_float4(0.f, 0.f, 0.f, 0.f);
    }
}

// ---------------- CSR build ----------------
__global__ __launch_bounds__(256) void scan1_kernel(const int* __restrict__ counts,
                                                    int* __restrict__ row_ptr,
                                                    int* __restrict__ bsums){
    __shared__ int s[256];
    int t = threadIdx.x;
    int i = blockIdx.x * 256 + t;
    int v = (i < NNODES) ? counts[i] : 0;
    s[t] = v; __syncthreads();
    for (int off = 1; off < 256; off <<= 1) {
        int a = (t >= off) ? s[t - off] : 0;
        __syncthreads();
        s[t] += a;
        __syncthreads();
    }
    if (i < NNODES) row_ptr[i] = s[t] - v;
    if (t == 255) bsums[blockIdx.x] = s[255];
}

__global__ __launch_bounds__(512) void scan2_kernel(const int* __restrict__ bsums,
                                                    int* __restrict__ boffs, int nb){
    __shared__ int s[512];
    int t = threadIdx.x;
    int v = (t < nb) ? bsums[t] : 0;
    s[t] = v; __syncthreads();
    for (int off = 1; off < 512; off <<= 1) {
        int a = (t >= off) ? s[t - off] : 0;
        __syncthreads();
        s[t] += a;
        __syncthreads();
    }
    if (t < nb) boffs[t] = s[t] - v;
}

__global__ __launch_bounds__(256) void scan3_kernel(int* __restrict__ row_ptr,
                                                    const int* __restrict__ boffs,
                                                    int* __restrict__ cursor){
    int i = blockIdx.x * 256 + threadIdx.x;
    if (i < NNODES) {
        int r = row_ptr[i] + boffs[blockIdx.x];
        row_ptr[i] = r;
        cursor[i]  = r;
    }
}

__global__ __launch_bounds__(256) void fill_kernel(const int* __restrict__ src,
                                                   const int* __restrict__ tgt,
                                                   int* __restrict__ cursor,
                                                   int* __restrict__ es){
    int e = blockIdx.x * 256 + threadIdx.x;
    if (e < NEDGES) {
        int pos = atomicAdd(&cursor[tgt[e]], 1);
        es[pos] = src[e];
    }
}

// ========== persistent conv: ALL weights in registers, grid-stride tiles ======
// Per wave: 40 A-fragments resident (wu0/wu1 64 + wc 64 + wg 32 = 160 VGPR),
// loaded ONCE per block. Inner loop per 32-node tile:
//   loop1: 8 xs B-reads, each feeding 3 MFMAs (U-et0, U-et1, G) -> us + aG
//   B1; commit prefetched next-x into xs; loop2: 16 us B-reads x We2 -> aT;
//   combine+M-write; B2. Next tile's x is prefetched into regs before loop1,
//   so global latency hides under the MFMA phases. MFMA order per accumulator
//   is bit-identical to the previous version.
// __launch_bounds__(256,2): 256-VGPR cap, 2 blocks/CU (8 waves/CU).
struct ConvW { short8 wu0[8], wu1[8], wc[16], wg[8]; };

__device__ __forceinline__ void load_w(ConvW& W, const u16* __restrict__ pwg,
                                       const u16* __restrict__ pwe1,
                                       const u16* __restrict__ pwe2,
                                       int w, int lane){
#pragma unroll
    for (int ks = 0; ks < 8; ks++) {
        W.wu0[ks] = *(const short8*)(pwe1 + (((ks * 8 + w) * 64 + lane) << 3));
        W.wu1[ks] = *(const short8*)(pwe1 + (((ks * 8 + w + 4) * 64 + lane) << 3));
        W.wg[ks]  = *(const short8*)(pwg  + (((ks * 4 + w) * 64 + lane) << 3));
    }
#pragma unroll
    for (int jj = 0; jj < 16; jj++)
        W.wc[jj] = *(const short8*)(pwe2 + (((jj * 4 + w) * 64 + lane) << 3));
}

__device__ __forceinline__ void conv_loop1(const ConvW& W, const u16* xs, u16* us,
                                           int w, int lane, f32x16& aG_out){
    const int half = lane >> 5, nn = lane & 31;
    f32x16 acc0 = {}, acc1 = {}, g = {};
#pragma unroll
    for (int ks = 0; ks < 8; ks++) {
        short8 B = *(const short8*)(&xs[cidx(ks * 2 + half, nn)]);
        acc0 = __builtin_amdgcn_mfma_f32_32x32x16_bf16(W.wu0[ks], B, acc0, 0, 0, 0);
        acc1 = __builtin_amdgcn_mfma_f32_32x32x16_bf16(W.wu1[ks], B, acc1, 0, 0, 0);
        g    = __builtin_amdgcn_mfma_f32_32x32x16_bf16(W.wg[ks],  B, g,    0, 0, 0);
    }
#pragma unroll
    for (int q = 0; q < 4; q++) {
        uint2 d;
        d.x = pack2(sp_f(acc0[q*4+0]), sp_f(acc0[q*4+1]));
        d.y = pack2(sp_f(acc0[q*4+2]), sp_f(acc0[q*4+3]));
        *(uint2*)(&us[cidx(w * 4 + q, nn) + half * 4]) = d;
        uint2 e;
        e.x = pack2(sp_f(acc1[q*4+0]), sp_f(acc1[q*4+1]));
        e.y = pack2(sp_f(acc1[q*4+2]), sp_f(acc1[q*4+3]));
        *(uint2*)(&us[cidx(16 + w * 4 + q, nn) + half * 4]) = e;
    }
    aG_out = g;
}

__device__ __forceinline__ void conv_loop2(const ConvW& W, const u16* us,
                                           const f32x16& aG, u16* __restrict__ M,
                                           long row0, int w, int lane){
    const int half = lane >> 5, nn = lane & 31;
    f32x16 aT = {};
#pragma unroll
    for (int jj = 0; jj < 16; jj++) {
        short8 B = *(const short8*)(&us[cidx(jj * 2 + half, nn)]);
        aT = __builtin_amdgcn_mfma_f32_32x32x16_bf16(W.wc[jj], B, aT, 0, 0, 0);
    }
    long node = row0 + nn;                         // 3125*32 == NNODES exactly
#pragma unroll
    for (int q = 0; q < 4; q++) {
        int h0 = w * 32 + half * 4 + q * 8;
        uint2 d;
        d.x = pack2(sig_f(aG[q*4+0]) * sp_f(aT[q*4+0]),
                    sig_f(aG[q*4+1]) * sp_f(aT[q*4+1]));
        d.y = pack2(sig_f(aG[q*4+2]) * sp_f(aT[q*4+2]),
                    sig_f(aG[q*4+3]) * sp_f(aT[q*4+3]));
        *(uint2*)(M + node * HF + h0) = d;
    }
}

// ---------------- conv0: embed fused; persistent; writes x and M ----------------
__global__ __launch_bounds__(256, 2) void conv0_mfma(const int* __restrict__ nodes,
                                                     const void* __restrict__ emb,
                                                     u16* __restrict__ x,
                                                     const u16* __restrict__ pwg,
                                                     const u16* __restrict__ pwe1,
                                                     const u16* __restrict__ pwe2,
                                                     u16* __restrict__ M){
    __shared__ u16 xs[16 * PLD];   //  8,448 B
    __shared__ u16 us[32 * PLD];   // 16,896 B
    const int t = threadIdx.x;
    const int w = t >> 6, lane = t & 63;
    const int r0 = t >> 4, q = t & 15;             // rows r0 and r0+16, chunk q
    const bool f32 = is_f32(emb);

    ConvW W;
    load_w(W, pwg, pwe1, pwe2, w, lane);

    const float4* ef = (const float4*)emb;
    const uint4*  eu = (const uint4*)emb;
    uint4* xg = (uint4*)x;

    int tile = blockIdx.x;
    // initial stage of first tile
    {
        long row0 = (long)tile * 32;
        int v0 = nodes[row0 + r0], v1 = nodes[row0 + r0 + 16];
        uint4 b0, b1;
        if (f32) {
            float4 f0 = ef[(long)v0 * 32 + q * 2], f1 = ef[(long)v0 * 32 + q * 2 + 1];
            float4 f2 = ef[(long)v1 * 32 + q * 2], f3 = ef[(long)v1 * 32 + q * 2 + 1];
            b0.x = pack2(f0.x, f0.y); b0.y = pack2(f0.z, f0.w);
            b0.z = pack2(f1.x, f1.y); b0.w = pack2(f1.z, f1.w);
            b1.x = pack2(f2.x, f2.y); b1.y = pack2(f2.z, f2.w);
            b1.z = pack2(f3.x, f3.y); b1.w = pack2(f3.z, f3.w);
        } else {
            b0 = eu[(long)v0 * 16 + q];
            b1 = eu[(long)v1 * 16 + q];
        }
        xg[(row0 + r0) * 16 + q] = b0;
        xg[(row0 + r0 + 16) * 16 + q] = b1;
        *(uint4*)(&xs[cidx(q, r0)]) = b0;
        *(uint4*)(&xs[cidx(q, r0 + 16)]) = b1;
    }
    __syncthreads();

    for (;;) {
        long row0 = (long)tile * 32;
        int nxt = tile + GRID_CONV;
        bool have = nxt < NTILES;
        uint4 nb0 = {}, nb1 = {};
        float4 nf0 = {}, nf1 = {}, nf2 = {}, nf3 = {};
        if (have) {                                // issue next-tile loads early
            long nr = (long)nxt * 32;
            int v0 = nodes[nr + r0], v1 = nodes[nr + r0 + 16];
            if (f32) {
                nf0 = ef[(long)v0 * 32 + q * 2]; nf1 = ef[(long)v0 * 32 + q * 2 + 1];
                nf2 = ef[(long)v1 * 32 + q * 2]; nf3 = ef[(long)v1 * 32 + q * 2 + 1];
            } else {
                nb0 = eu[(long)v0 * 16 + q];
                nb1 = eu[(long)v1 * 16 + q];
            }
        }
        f32x16 aG;
        conv_loop1(W, xs, us, w, lane, aG);
        __syncthreads();                           // B1: us ready, xs reads done
        if (have) {
            uint4 b0 = nb0, b1 = nb1;
            if (f32) {
                b0.x = pack2(nf0.x, nf0.y); b0.y = pack2(nf0.z, nf0.w);
                b0.z = pack2(nf1.x, nf1.y); b0.w = pack2(nf1.z, nf1.w);
                b1.x = pack2(nf2.x, nf2.y); b1.y = pack2(nf2.z, nf2.w);
                b1.z = pack2(nf3.x, nf3.y); b1.w = pack2(nf3.z, nf3.w);
            }
            long nr = (long)nxt * 32;
            xg[(nr + r0) * 16 + q] = b0;
            xg[(nr + r0 + 16) * 16 + q] = b1;
            *(uint4*)(&xs[cidx(q, r0)]) = b0;
            *(uint4*)(&xs[cidx(q, r0 + 16)]) = b1;
        }
        conv_loop2(W, us, aG, M, row0, w, lane);
        if (!have) break;
        __syncthreads();                           // B2: xs ready, us reads done
        tile = nxt;
    }
}

// ---------------- conv: stages x from global; persistent; writes M ----------------
__global__ __launch_bounds__(256, 2) void conv_mfma(const u16* __restrict__ x,
                                                    const u16* __restrict__ pwg,
                                                    const u16* __restrict__ pwe1,
                                                    const u16* __restrict__ pwe2,
                                                    u16* __restrict__ M){
    __shared__ u16 xs[16 * PLD];
    __shared__ u16 us[32 * PLD];
    const int t = threadIdx.x;
    const int w = t >> 6, lane = t & 63;
    const int r0 = t >> 4, q = t & 15;

    ConvW W;
    load_w(W, pwg, pwe1, pwe2, w, lane);

    const uint4* xg = (const uint4*)x;
    int tile = blockIdx.x;
    {
        long row0 = (long)tile * 32;
        uint4 b0 = xg[(row0 + r0) * 16 + q];
        uint4 b1 = xg[(row0 + r0 + 16) * 16 + q];
        *(uint4*)(&xs[cidx(q, r0)]) = b0;
        *(uint4*)(&xs[cidx(q, r0 + 16)]) = b1;
    }
    __syncthreads();

    for (;;) {
        long row0 = (long)tile * 32;
        int nxt = tile + GRID_CONV;
        bool have = nxt < NTILES;
        uint4 nb0 = {}, nb1 = {};
        if (have) {                                // issue next-tile loads early
            long nr = (long)nxt * 32;
            nb0 = xg[(nr + r0) * 16 + q];
            nb1 = xg[(nr + r0 + 16) * 16 + q];
        }
        f32x16 aG;
        conv_loop1(W, xs, us, w, lane, aG);
        __syncthreads();                           // B1: us ready, xs reads done
        if (have) {
            *(uint4*)(&xs[cidx(q, r0)]) = nb0;
            *(uint4*)(&xs[cidx(q, r0 + 16)]) = nb1;
        }
        conv_loop2(W, us, aG, M, row0, w, lane);
        if (!have) break;
        __syncthreads();                           // B2: xs ready, us reads done
        tile = nxt;
    }
}

// ---------------- aggregation: x[v] += sp( sum_{e: tgt=v} M[src[e]] ) ----------------
// uint4 per lane, 16 lanes per node row, 4 nodes per wave, 4x-unrolled gather.
__global__ __launch_bounds__(256) void agg_kernel(const u16* __restrict__ M,
                                                  const int* __restrict__ row_ptr,
                                                  const int* __restrict__ counts,
                                                  const int* __restrict__ es,
                                                  u16* __restrict__ x){
    int wid = blockIdx.x * 4 + (threadIdx.x >> 6);
    int lane = threadIdx.x & 63;
    long v = (long)wid * 4 + (lane >> 4);
    int l = lane & 15;
    if (v >= NNODES) return;
    int start = row_ptr[v], cnt = counts[v];
    float a0=0.f,a1=0.f,a2=0.f,a3=0.f,a4=0.f,a5=0.f,a6=0.f,a7=0.f;
    float b0=0.f,b1=0.f,b2=0.f,b3=0.f,b4=0.f,b5=0.f,b6=0.f,b7=0.f;
    const uint4* Mu = (const uint4*)M;
    int e = 0;
    for (; e + 3 < cnt; e += 4) {
        int s0 = es[start + e],     s1 = es[start + e + 1];
        int s2 = es[start + e + 2], s3 = es[start + e + 3];
        uint4 u0 = Mu[(long)s0 * 16 + l];
        uint4 u1 = Mu[(long)s1 * 16 + l];
        uint4 u2 = Mu[(long)s2 * 16 + l];
        uint4 u3 = Mu[(long)s3 * 16 + l];
        a0 += bfu((u16)u0.x); a1 += bfu((u16)(u0.x >> 16));
        a2 += bfu((u16)u0.y); a3 += bfu((u16)(u0.y >> 16));
        a4 += bfu((u16)u0.z); a5 += bfu((u16)(u0.z >> 16));
        a6 += bfu((u16)u0.w); a7 += bfu((u16)(u0.w >> 16));
        b0 += bfu((u16)u1.x); b1 += bfu((u16)(u1.x >> 16));
        b2 += bfu((u16)u1.y); b3 += bfu((u16)(u1.y >> 16));
        b4 += bfu((u16)u1.z); b5 += bfu((u16)(u1.z >> 16));
        b6 += bfu((u16)u1.w); b7 += bfu((u16)(u1.w >> 16));
        a0 += bfu((u16)u2.x); a1 += bfu((u16)(u2.x >> 16));
        a2 += bfu((u16)u2.y); a3 += bfu((u16)(u2.y >> 16));
        a4 += bfu((u16)u2.z); a5 += bfu((u16)(u2.z >> 16));
        a6 += bfu((u16)u2.w); a7 += bfu((u16)(u2.w >> 16));
        b0 += bfu((u16)u3.x); b1 += bfu((u16)(u3.x >> 16));
        b2 += bfu((u16)u3.y); b3 += bfu((u16)(u3.y >> 16));
        b4 += bfu((u16)u3.z); b5 += bfu((u16)(u3.z >> 16));
        b6 += bfu((u16)u3.w); b7 += bfu((u16)(u3.w >> 16));
    }
    for (; e < cnt; e++) {
        int s0 = es[start + e];
        uint4 u0 = Mu[(long)s0 * 16 + l];
        a0 += bfu((u16)u0.x); a1 += bfu((u16)(u0.x >> 16));
        a2 += bfu((u16)u0.y); a3 += bfu((u16)(u0.y >> 16));
        a4 += bfu((u16)u0.z); a5 += bfu((u16)(u0.z >> 16));
        a6 += bfu((u16)u0.w); a7 += bfu((u16)(u0.w >> 16));
    }
    a0 += b0; a1 += b1; a2 += b2; a3 += b3;
    a4 += b4; a5 += b5; a6 += b6; a7 += b7;
    uint4* xu = (uint4*)x;
    uint4 xv = xu[v * 16 + l];
    xv.x = pack2(bfu((u16)xv.x) + sp_f(a0), bfu((u16)(xv.x >> 16)) + sp_f(a1));
    xv.y = pack2(bfu((u16)xv.y) + sp_f(a2), bfu((u16)(xv.y >> 16)) + sp_f(a3));
    xv.z = pack2(bfu((u16)xv.z) + sp_f(a4), bfu((u16)(xv.z >> 16)) + sp_f(a5));
    xv.w = pack2(bfu((u16)xv.w) + sp_f(a6), bfu((u16)(xv.w >> 16)) + sp_f(a7));
    xu[v * 16 + l] = xv;
}

// ---------------- pooling: xsum[g] = sum of x rows of graph g (atomic flush) ----------------
__global__ __launch_bounds__(256) void pool_kernel(const u16* __restrict__ x,
                                                   const int* __restrict__ gidx,
                                                   float* __restrict__ xsum){
    int wave = blockIdx.x * 4 + (threadIdx.x >> 6);
    int lane = threadIdx.x & 63;
    long base = (long)wave * 64;
    if (base >= NNODES) return;
    long end = base + 64; if (end > NNODES) end = NNODES;
    const unsigned* xu = (const unsigned*)x;
    int gcur = gidx[base];
    float a0 = 0.f, a1 = 0.f;
    for (long v = base; v < end; v++) {
        int g = gidx[v];                           // wave-uniform
        if (g != gcur) {
            atomicAdd(&xsum[gcur * HF + lane * 2 + 0], a0);
            atomicAdd(&xsum[gcur * HF + lane * 2 + 1], a1);
            a0 = a1 = 0.f; gcur = g;
        }
        unsigned u = xu[v * 64 + lane];
        a0 += bfu((u16)u);
        a1 += bfu((u16)(u >> 16));
    }
    atomicAdd(&xsum[gcur * HF + lane * 2 + 0], a0);
    atomicAdd(&xsum[gcur * HF + lane * 2 + 1], a1);
}

// ---------------- head via transposed 16x16 MFMA, bf16 hi+lo activations ----------------
__global__ __launch_bounds__(256) void head_mfma(const float* __restrict__ xsum,
                                                 const void* __restrict__ ncnt,
                                                 const u16* __restrict__ pwp,
                                                 const u16* __restrict__ pf1,
                                                 const u16* __restrict__ pf2,
                                                 const void* __restrict__ bfc1,
                                                 const void* __restrict__ bfc2,
                                                 const void* __restrict__ Wr,
                                                 const void* __restrict__ br,
                                                 void* __restrict__ out,
                                                 const void* __restrict__ probe){
    __shared__ u16 hibuf[2][GB][136];
    __shared__ u16 lobuf[2][GB][136];
    const int t = threadIdx.x;
    const int w = t >> 6, lane = t & 63;
    const int quad = lane >> 4, nr = lane & 15;
    const bool f32 = is_f32(probe);
    const int g0 = blockIdx.x * GB;

    for (int i = t; i < GB * 64; i += 256) {
        int g = i >> 6, c = (i & 63) * 2;
        float f0 = xsum[(g0 + g) * HF + c], f1 = xsum[(g0 + g) * HF + c + 1];
        u16 h0 = f2bf(f0), h1 = f2bf(f1);
        *(unsigned*)&hibuf[0][g][c] = (unsigned)h0 | ((unsigned)h1 << 16);
        *(unsigned*)&lobuf[0][g][c] = pack2(f0 - bfu(h0), f1 - bfu(h1));
    }
    __syncthreads();

    float rc[2];
#pragma unroll
    for (int nt = 0; nt < 2; nt++) rc[nt] = RCP1(lf(ncnt, g0 + nt * 16 + nr, f32));

    int cur = 0;
    for (int layer = 0; layer < 3; layer++) {
        const u16* pw = (layer == 0) ? pwp : (layer == 1) ? pf1 : pf2;
        const void* bias = (layer == 1) ? bfc1 : bfc2;
        int nxt = cur ^ 1;
#pragma unroll
        for (int c = 0; c < 2; c++) {
            int et = w * 2 + c;
            short8 A[4];
#pragma unroll
            for (int kt = 0; kt < 4; kt++)
                A[kt] = *(const short8*)(pw + (((kt * 8 + et) * 64 + lane) << 3));
#pragma unroll
            for (int nt = 0; nt < 2; nt++) {
                f32x4 acc = {0.f, 0.f, 0.f, 0.f};
#pragma unroll
                for (int kt = 0; kt < 4; kt++) {
                    short8 bh = *(const short8*)(&hibuf[cur][nt * 16 + nr][kt * 32 + quad * 8]);
                    short8 bl = *(const short8*)(&lobuf[cur][nt * 16 + nr][kt * 32 + quad * 8]);
                    acc = __builtin_amdgcn_mfma_f32_16x16x32_bf16(A[kt], bh, acc, 0, 0, 0);
                    acc = __builtin_amdgcn_mfma_f32_16x16x32_bf16(A[kt], bl, acc, 0, 0, 0);
                }
                int feat0 = et * 16 + quad * 4;
                float f[4];
#pragma unroll
                for (int r = 0; r < 4; r++) {
                    float a = (layer == 0) ? acc[r] * rc[nt]
                                           : acc[r] + lf(bias, feat0 + r, f32);
                    f[r] = sp_f(a);
                }
                u16 h[4]; float lo[4];
#pragma unroll
                for (int r = 0; r < 4; r++) { h[r] = f2bf(f[r]); lo[r] = f[r] - bfu(h[r]); }
                uint2 dh, dl;
                dh.x = (unsigned)h[0] | ((unsigned)h[1] << 16);
                dh.y = (unsigned)h[2] | ((unsigned)h[3] << 16);
                dl.x = pack2(lo[0], lo[1]);
                dl.y = pack2(lo[2], lo[3]);
                *(uint2*)&hibuf[nxt][nt * 16 + nr][feat0] = dh;
                *(uint2*)&lobuf[nxt][nt * 16 + nr][feat0] = dl;
            }
        }
        __syncthreads();
        cur = nxt;
    }

    int g = t >> 3, sub = t & 7;
    float p = 0.f;
    for (int k = sub * 16; k < sub * 16 + 16; k++) {
        float v = bfu(hibuf[cur][g][k]) + bfu(lobuf[cur][g][k]);
        p += v * lf(Wr, k, f32);
    }
    p += __shfl_down(p, 4, 64);
    p += __shfl_down(p, 2, 64);
    p += __shfl_down(p, 1, 64);
    if (sub == 0) {
        float res = p + lf(br, 0, f32);
        if (f32) ((float*)out)[g0 + g] = res;
        else     ((u16*)out)[g0 + g]  = f2bf(res);
    }
}

extern "C" void kernel_launch(void* const* d_in, const int* in_sizes, int n_in,
                              void* d_out, int out_size, void* d_ws, size_t ws_size,
                              hipStream_t stream) {
    const int* nodes = (const int*)d_in[0];
    const int* esrc  = (const int*)d_in[1];
    const int* etgt  = (const int*)d_in[2];
    const int* gidx  = (const int*)d_in[3];

    size_t off = 0;
    char* w = (char*)d_ws;
    auto take = [&](size_t bytes) -> void* {
        void* p = w + off;
        off = (off + bytes + 255) & ~(size_t)255;
        return p;
    };

    u16* pwg     = (u16*)take((size_t)3 * HF * HF * 2);
    u16* pwe1    = (u16*)take((size_t)3 * HF * EF * 2);
    u16* pwe2    = (u16*)take((size_t)3 * EF * HF * 2);
    u16* pwp     = (u16*)take((size_t)HF * HF * 2);
    u16* pf1     = (u16*)take((size_t)HF * HF * 2);
    u16* pf2     = (u16*)take((size_t)HF * HF * 2);
    int* counts  = (int*)take((size_t)NNODES * 4);
    int* row_ptr = (int*)take((size_t)NNODES * 4);
    int* cursor  = (int*)take((size_t)NNODES * 4);
    int* es      = (int*)take((size_t)NEDGES * 4);
    int* bsums   = (int*)take(2048);
    int* boffs   = (int*)take(2048);
    float* xsum  = (float*)take((size_t)NGRAPHS * HF * 4);
    u16* x       = (u16*)take((size_t)NNODES * HF * 2);
    u16* M       = (u16*)take((size_t)NNODES * HF * 2);

    hipMemsetAsync(counts, 0, (size_t)NNODES * 4, stream);

    // prep: conv repack (960) + head repack (192) + count (2344) + xsum zero (64)
    prep_kernel<<<3560, 256, 0, stream>>>(d_in[6], d_in[7], d_in[8],
                                          d_in[9], d_in[10], d_in[12],
                                          pwg, pwe1, pwe2, pwp, pf1, pf2,
                                          d_in[5], etgt, counts, xsum);

    const int NB_SCAN = (NNODES + 255) / 256;      // 391
    const int NB_EDGE = (NEDGES + 255) / 256;      // 2344
    scan1_kernel<<<NB_SCAN, 256, 0, stream>>>(counts, row_ptr, bsums);
    scan2_kernel<<<1, 512, 0, stream>>>(bsums, boffs, NB_SCAN);
    scan3_kernel<<<NB_SCAN, 256, 0, stream>>>(row_ptr, boffs, cursor);
    fill_kernel<<<NB_EDGE, 256, 0, stream>>>(esrc, etgt, cursor, es);

    const int NBA = (NNODES + 15) / 16;            // 6250
    conv0_mfma<<<GRID_CONV, 256, 0, stream>>>(nodes, d_in[5], x, pwg, pwe1, pwe2, M);
    agg_kernel<<<NBA, 256, 0, stream>>>(M, row_ptr, counts, es, x);
    conv_mfma<<<GRID_CONV, 256, 0, stream>>>(x,
        pwg + (size_t)1 * HF * HF, pwe1 + (size_t)1 * HF * EF, pwe2 + (size_t)1 * EF * HF, M);
    agg_kernel<<<NBA, 256, 0, stream>>>(M, row_ptr, counts, es, x);
    conv_mfma<<<GRID_CONV, 256, 0, stream>>>(x,
        pwg + (size_t)2 * HF * HF, pwe1 + (size_t)2 * HF * EF, pwe2 + (size_t)2 * EF * HF, M);
    agg_kernel<<<NBA, 256, 0, stream>>>(M, row_ptr, counts, es, x);

    pool_kernel<<<(NNODES + 255) / 256, 256, 0, stream>>>(x, gidx, xsum);
    head_mfma<<<NGRAPHS / GB, 256, 0, stream>>>(xsum, d_in[4], pwp, pf1, pf2,
                                                d_in[11], d_in[13], d_in[14], d_in[15],
                                                d_out, d_in[5]);
}

// Round 5
// 387.797 us; speedup vs baseline: 1.0257x; 1.0005x over previous
//
#include <hip/hip_runtime.h>
#include <hip/hip_bf16.h>

typedef unsigned short u16;
typedef __attribute__((ext_vector_type(8))) short short8;
typedef __attribute__((ext_vector_type(4))) float f32x4;
typedef __attribute__((ext_vector_type(16))) float f32x16;
typedef __attribute__((ext_vector_type(2))) __bf16 bf16x2;

#define NNODES 100000
#define NEDGES 600000
#define NGRAPHS 512
#define HF 128
#define EF 256
#define GB 32       // graphs per head block
#define NTILES 3125 // 100000 / 32
#define GRID_CONV 512

// chunk-major LDS planes, 32-node tiles: plane = 32 rows x 16B + 16B pad
// -> stride 264 u16 (528 B = 132 dwords == 4 banks mod 32)
#define PLD 264
__device__ __forceinline__ int cidx(int chunk, int row){ return chunk * PLD + row * 8; }

__device__ __forceinline__ float bfu(u16 u){ return __uint_as_float(((unsigned)u) << 16); }
__device__ __forceinline__ u16 f2bf(float f){
    unsigned u = __float_as_uint(f);
    unsigned r = (u + 0x7fff + ((u >> 16) & 1)) >> 16;
    return (u16)r;
}
// HW packed f32->bf16 RNE (v_cvt_pk_bf16_f32 on gfx950)
__device__ __forceinline__ unsigned pack2(float a, float b){
    bf16x2 v = { (__bf16)a, (__bf16)b };
    return __builtin_bit_cast(unsigned, v);
}

#if __has_builtin(__builtin_amdgcn_rcpf)
#define RCP1(x) __builtin_amdgcn_rcpf(x)
#else
#define RCP1(x) (1.f / (x))
#endif

// cheap softplus: log(1+exp(x)) direct — safe for |x| << 80 (values here <~20)
__device__ __forceinline__ float sp_f(float x){
    return __logf(1.f + __expf(x));
}
__device__ __forceinline__ float sig_f(float x){
    return RCP1(1.f + __expf(-x));
}
__device__ __forceinline__ float lf(const void* p, long i, bool f32){
    return f32 ? ((const float*)p)[i] : bfu(((const u16*)p)[i]);
}

// in-register dtype detection: probe 256 u16 of the embed table as bf16
__device__ __forceinline__ bool is_f32(const void* probe){
    const u16* p = (const u16*)probe;
    int lane = threadIdx.x & 63;
    int c = 0;
#pragma unroll
    for (int i = 0; i < 4; i++) c += (fabsf(bfu(p[lane * 4 + i])) > 1.0f) ? 1 : 0;
#pragma unroll
    for (int off = 32; off; off >>= 1) c += __shfl_xor(c, off, 64);
    return c > 8;
}

// ---------------- prep: weight repack + edge count + xsum zero ----------------
// conv weights -> 32x32x16 A-frag order: P[ks][nt32][lane][8]; lane l holds
//   W[k = ks*16 + (l>>5)*8 + j][n = nt32*32 + (l&31)], j=0..7  (W^T as A operand)
// head weights -> 16x16x32 frag order.
// blocks [0,960): conv; [960,1152): head; [1152,3496): edge count;
// [3496,3560): zero xsum (64 blocks x 256 x float4)
__global__ __launch_bounds__(256) void prep_kernel(const void* __restrict__ wg,
                                                   const void* __restrict__ we1,
                                                   const void* __restrict__ we2,
                                                   const void* __restrict__ wp,
                                                   const void* __restrict__ wfc1,
                                                   const void* __restrict__ wfc2,
                                                   u16* __restrict__ pwg,
                                                   u16* __restrict__ pwe1,
                                                   u16* __restrict__ pwe2,
                                                   u16* __restrict__ pwp,
                                                   u16* __restrict__ pf1,
                                                   u16* __restrict__ pf2,
                                                   const void* __restrict__ emb,
                                                   const int* __restrict__ tgt,
                                                   int* __restrict__ counts,
                                                   float* __restrict__ xsum){
    int b = blockIdx.x, t = threadIdx.x;
    if (b < 960) {
        bool f32 = is_f32(emb);
        int i = b * 256 + t;                       // < 3*81920
        int c = i / 81920, r = i % 81920;
        const void* src; u16* dst; int N, KN, l;
        if (r < 16384)      { src = wg;  dst = pwg;  N = HF; KN = 16384; l = r; }
        else if (r < 49152) { src = we1; dst = pwe1; N = EF; KN = 32768; l = r - 16384; }
        else                { src = we2; dst = pwe2; N = HF; KN = 32768; l = r - 49152; }
        int j = l & 7, lane = (l >> 3) & 63, rest = l >> 9;
        int NT = N >> 5;
        int nt = rest % NT, ks = rest / NT;
        int k = ks * 16 + (lane >> 5) * 8 + j;
        int n = nt * 32 + (lane & 31);
        long base = (long)c * KN;
        dst[base + l] = f2bf(lf(src, base + (long)k * N + n, f32));
    } else if (b < 1152) {
        bool f32 = is_f32(emb);
        int i = (b - 960) * 256 + t;               // < 3*16384
        int c = i / 16384, l = i % 16384;
        const void* src = (c == 0) ? wp : (c == 1) ? wfc1 : wfc2;
        u16* dst = (c == 0) ? pwp : (c == 1) ? pf1 : pf2;
        int j = l & 7, lane = (l >> 3) & 63, rest = l >> 9;
        int nt = rest & 7, kt = rest >> 3;         // 16x16 layout, N=128
        int k = kt * 32 + (lane >> 4) * 8 + j;
        int n = nt * 16 + (lane & 15);
        dst[l] = f2bf(lf(src, (long)k * HF + n, f32));
    } else if (b < 3496) {
        int e = (b - 1152) * 256 + t;
        if (e < NEDGES) atomicAdd(&counts[tgt[e]], 1);
    } else {
        int i = (b - 3496) * 256 + t;              // < 16384 float4s
        ((float4*)xsum)[i] = make_float4(0.f, 0.f, 0.f, 0.f);
    }
}

// ---------------- CSR build ----------------
__global__ __launch_bounds__(256) void scan1_kernel(const int* __restrict__ counts,
                                                    int* __restrict__ row_ptr,
                                                    int* __restrict__ bsums){
    __shared__ int s[256];
    int t = threadIdx.x;
    int i = blockIdx.x * 256 + t;
    int v = (i < NNODES) ? counts[i] : 0;
    s[t] = v; __syncthreads();
    for (int off = 1; off < 256; off <<= 1) {
        int a = (t >= off) ? s[t - off] : 0;
        __syncthreads();
        s[t] += a;
        __syncthreads();
    }
    if (i < NNODES) row_ptr[i] = s[t] - v;
    if (t == 255) bsums[blockIdx.x] = s[255];
}

__global__ __launch_bounds__(512) void scan2_kernel(const int* __restrict__ bsums,
                                                    int* __restrict__ boffs, int nb){
    __shared__ int s[512];
    int t = threadIdx.x;
    int v = (t < nb) ? bsums[t] : 0;
    s[t] = v; __syncthreads();
    for (int off = 1; off < 512; off <<= 1) {
        int a = (t >= off) ? s[t - off] : 0;
        __syncthreads();
        s[t] += a;
        __syncthreads();
    }
    if (t < nb) boffs[t] = s[t] - v;
}

__global__ __launch_bounds__(256) void scan3_kernel(int* __restrict__ row_ptr,
                                                    const int* __restrict__ boffs,
                                                    int* __restrict__ cursor){
    int i = blockIdx.x * 256 + threadIdx.x;
    if (i < NNODES) {
        int r = row_ptr[i] + boffs[blockIdx.x];
        row_ptr[i] = r;
        cursor[i]  = r;
    }
}

__global__ __launch_bounds__(256) void fill_kernel(const int* __restrict__ src,
                                                   const int* __restrict__ tgt,
                                                   int* __restrict__ cursor,
                                                   int* __restrict__ es){
    int e = blockIdx.x * 256 + threadIdx.x;
    if (e < NEDGES) {
        int pos = atomicAdd(&cursor[tgt[e]], 1);
        es[pos] = src[e];
    }
}

// ========== persistent conv: ALL weights in registers, grid-stride tiles ======
// R4 lesson: the compiler REMATERIALIZED load_w into the loop (VGPR_Count=128
// < 160 needed) — weights were still re-fetched from L2 every tile. This round
// forces residency with inline-asm keep-alives: the asm makes each fragment's
// definition opaque so it cannot be rematerialized; the allocator must keep
// all 40 fragments (160 VGPRs) live across the tile loop.
// __launch_bounds__(256,2): 256-VGPR cap, 2 blocks/CU (8 waves/CU).
struct ConvW { short8 wu0[8], wu1[8], wc[16], wg[8]; };

#define KEEP(x) asm volatile("" : "+v"(x))

__device__ __forceinline__ void load_w(ConvW& W, const u16* __restrict__ pwg,
                                       const u16* __restrict__ pwe1,
                                       const u16* __restrict__ pwe2,
                                       int w, int lane){
#pragma unroll
    for (int ks = 0; ks < 8; ks++) {
        W.wu0[ks] = *(const short8*)(pwe1 + (((ks * 8 + w) * 64 + lane) << 3));
        W.wu1[ks] = *(const short8*)(pwe1 + (((ks * 8 + w + 4) * 64 + lane) << 3));
        W.wg[ks]  = *(const short8*)(pwg  + (((ks * 4 + w) * 64 + lane) << 3));
    }
#pragma unroll
    for (int jj = 0; jj < 16; jj++)
        W.wc[jj] = *(const short8*)(pwe2 + (((jj * 4 + w) * 64 + lane) << 3));
    // force residency: opaque defs cannot be rematerialized into the loop
#pragma unroll
    for (int ks = 0; ks < 8; ks++) { KEEP(W.wu0[ks]); KEEP(W.wu1[ks]); KEEP(W.wg[ks]); }
#pragma unroll
    for (int jj = 0; jj < 16; jj++) { KEEP(W.wc[jj]); }
}

__device__ __forceinline__ void conv_loop1(const ConvW& W, const u16* xs, u16* us,
                                           int w, int lane, f32x16& aG_out){
    const int half = lane >> 5, nn = lane & 31;
    f32x16 acc0 = {}, acc1 = {}, g = {};
#pragma unroll
    for (int ks = 0; ks < 8; ks++) {
        short8 B = *(const short8*)(&xs[cidx(ks * 2 + half, nn)]);
        acc0 = __builtin_amdgcn_mfma_f32_32x32x16_bf16(W.wu0[ks], B, acc0, 0, 0, 0);
        acc1 = __builtin_amdgcn_mfma_f32_32x32x16_bf16(W.wu1[ks], B, acc1, 0, 0, 0);
        g    = __builtin_amdgcn_mfma_f32_32x32x16_bf16(W.wg[ks],  B, g,    0, 0, 0);
    }
#pragma unroll
    for (int q = 0; q < 4; q++) {
        uint2 d;
        d.x = pack2(sp_f(acc0[q*4+0]), sp_f(acc0[q*4+1]));
        d.y = pack2(sp_f(acc0[q*4+2]), sp_f(acc0[q*4+3]));
        *(uint2*)(&us[cidx(w * 4 + q, nn) + half * 4]) = d;
        uint2 e;
        e.x = pack2(sp_f(acc1[q*4+0]), sp_f(acc1[q*4+1]));
        e.y = pack2(sp_f(acc1[q*4+2]), sp_f(acc1[q*4+3]));
        *(uint2*)(&us[cidx(16 + w * 4 + q, nn) + half * 4]) = e;
    }
    aG_out = g;
}

__device__ __forceinline__ void conv_loop2(const ConvW& W, const u16* us,
                                           const f32x16& aG, u16* __restrict__ M,
                                           long row0, int w, int lane){
    const int half = lane >> 5, nn = lane & 31;
    f32x16 aT = {};
#pragma unroll
    for (int jj = 0; jj < 16; jj++) {
        short8 B = *(const short8*)(&us[cidx(jj * 2 + half, nn)]);
        aT = __builtin_amdgcn_mfma_f32_32x32x16_bf16(W.wc[jj], B, aT, 0, 0, 0);
    }
    long node = row0 + nn;                         // 3125*32 == NNODES exactly
#pragma unroll
    for (int q = 0; q < 4; q++) {
        int h0 = w * 32 + half * 4 + q * 8;
        uint2 d;
        d.x = pack2(sig_f(aG[q*4+0]) * sp_f(aT[q*4+0]),
                    sig_f(aG[q*4+1]) * sp_f(aT[q*4+1]));
        d.y = pack2(sig_f(aG[q*4+2]) * sp_f(aT[q*4+2]),
                    sig_f(aG[q*4+3]) * sp_f(aT[q*4+3]));
        *(uint2*)(M + node * HF + h0) = d;
    }
}

// ---------------- conv0: embed fused; persistent; writes x and M ----------------
__global__ __launch_bounds__(256, 2) void conv0_mfma(const int* __restrict__ nodes,
                                                     const void* __restrict__ emb,
                                                     u16* __restrict__ x,
                                                     const u16* __restrict__ pwg,
                                                     const u16* __restrict__ pwe1,
                                                     const u16* __restrict__ pwe2,
                                                     u16* __restrict__ M){
    __shared__ u16 xs[16 * PLD];   //  8,448 B
    __shared__ u16 us[32 * PLD];   // 16,896 B
    const int t = threadIdx.x;
    const int w = t >> 6, lane = t & 63;
    const int r0 = t >> 4, q = t & 15;             // rows r0 and r0+16, chunk q
    const bool f32 = is_f32(emb);

    ConvW W;
    load_w(W, pwg, pwe1, pwe2, w, lane);

    const float4* ef = (const float4*)emb;
    const uint4*  eu = (const uint4*)emb;
    uint4* xg = (uint4*)x;

    int tile = blockIdx.x;
    // initial stage of first tile
    {
        long row0 = (long)tile * 32;
        int v0 = nodes[row0 + r0], v1 = nodes[row0 + r0 + 16];
        uint4 b0, b1;
        if (f32) {
            float4 f0 = ef[(long)v0 * 32 + q * 2], f1 = ef[(long)v0 * 32 + q * 2 + 1];
            float4 f2 = ef[(long)v1 * 32 + q * 2], f3 = ef[(long)v1 * 32 + q * 2 + 1];
            b0.x = pack2(f0.x, f0.y); b0.y = pack2(f0.z, f0.w);
            b0.z = pack2(f1.x, f1.y); b0.w = pack2(f1.z, f1.w);
            b1.x = pack2(f2.x, f2.y); b1.y = pack2(f2.z, f2.w);
            b1.z = pack2(f3.x, f3.y); b1.w = pack2(f3.z, f3.w);
        } else {
            b0 = eu[(long)v0 * 16 + q];
            b1 = eu[(long)v1 * 16 + q];
        }
        xg[(row0 + r0) * 16 + q] = b0;
        xg[(row0 + r0 + 16) * 16 + q] = b1;
        *(uint4*)(&xs[cidx(q, r0)]) = b0;
        *(uint4*)(&xs[cidx(q, r0 + 16)]) = b1;
    }
    __syncthreads();

    for (;;) {
        long row0 = (long)tile * 32;
        int nxt = tile + GRID_CONV;
        bool have = nxt < NTILES;
        uint4 nb0 = {}, nb1 = {};
        float4 nf0 = {}, nf1 = {}, nf2 = {}, nf3 = {};
        if (have) {                                // issue next-tile loads early
            long nr = (long)nxt * 32;
            int v0 = nodes[nr + r0], v1 = nodes[nr + r0 + 16];
            if (f32) {
                nf0 = ef[(long)v0 * 32 + q * 2]; nf1 = ef[(long)v0 * 32 + q * 2 + 1];
                nf2 = ef[(long)v1 * 32 + q * 2]; nf3 = ef[(long)v1 * 32 + q * 2 + 1];
            } else {
                nb0 = eu[(long)v0 * 16 + q];
                nb1 = eu[(long)v1 * 16 + q];
            }
        }
        f32x16 aG;
        conv_loop1(W, xs, us, w, lane, aG);
        __syncthreads();                           // B1: us ready, xs reads done
        if (have) {
            uint4 b0 = nb0, b1 = nb1;
            if (f32) {
                b0.x = pack2(nf0.x, nf0.y); b0.y = pack2(nf0.z, nf0.w);
                b0.z = pack2(nf1.x, nf1.y); b0.w = pack2(nf1.z, nf1.w);
                b1.x = pack2(nf2.x, nf2.y); b1.y = pack2(nf2.z, nf2.w);
                b1.z = pack2(nf3.x, nf3.y); b1.w = pack2(nf3.z, nf3.w);
            }
            long nr = (long)nxt * 32;
            xg[(nr + r0) * 16 + q] = b0;
            xg[(nr + r0 + 16) * 16 + q] = b1;
            *(uint4*)(&xs[cidx(q, r0)]) = b0;
            *(uint4*)(&xs[cidx(q, r0 + 16)]) = b1;
        }
        conv_loop2(W, us, aG, M, row0, w, lane);
        if (!have) break;
        __syncthreads();                           // B2: xs ready, us reads done
        tile = nxt;
    }
}

// ---------------- conv: stages x from global; persistent; writes M ----------------
__global__ __launch_bounds__(256, 2) void conv_mfma(const u16* __restrict__ x,
                                                    const u16* __restrict__ pwg,
                                                    const u16* __restrict__ pwe1,
                                                    const u16* __restrict__ pwe2,
                                                    u16* __restrict__ M){
    __shared__ u16 xs[16 * PLD];
    __shared__ u16 us[32 * PLD];
    const int t = threadIdx.x;
    const int w = t >> 6, lane = t & 63;
    const int r0 = t >> 4, q = t & 15;

    ConvW W;
    load_w(W, pwg, pwe1, pwe2, w, lane);

    const uint4* xg = (const uint4*)x;
    int tile = blockIdx.x;
    {
        long row0 = (long)tile * 32;
        uint4 b0 = xg[(row0 + r0) * 16 + q];
        uint4 b1 = xg[(row0 + r0 + 16) * 16 + q];
        *(uint4*)(&xs[cidx(q, r0)]) = b0;
        *(uint4*)(&xs[cidx(q, r0 + 16)]) = b1;
    }
    __syncthreads();

    for (;;) {
        long row0 = (long)tile * 32;
        int nxt = tile + GRID_CONV;
        bool have = nxt < NTILES;
        uint4 nb0 = {}, nb1 = {};
        if (have) {                                // issue next-tile loads early
            long nr = (long)nxt * 32;
            nb0 = xg[(nr + r0) * 16 + q];
            nb1 = xg[(nr + r0 + 16) * 16 + q];
        }
        f32x16 aG;
        conv_loop1(W, xs, us, w, lane, aG);
        __syncthreads();                           // B1: us ready, xs reads done
        if (have) {
            *(uint4*)(&xs[cidx(q, r0)]) = nb0;
            *(uint4*)(&xs[cidx(q, r0 + 16)]) = nb1;
        }
        conv_loop2(W, us, aG, M, row0, w, lane);
        if (!have) break;
        __syncthreads();                           // B2: xs ready, us reads done
        tile = nxt;
    }
}

// ---------------- aggregation: x[v] += sp( sum_{e: tgt=v} M[src[e]] ) ----------------
// uint4 per lane, 16 lanes per node row, 4 nodes per wave, 4x-unrolled gather.
__global__ __launch_bounds__(256) void agg_kernel(const u16* __restrict__ M,
                                                  const int* __restrict__ row_ptr,
                                                  const int* __restrict__ counts,
                                                  const int* __restrict__ es,
                                                  u16* __restrict__ x){
    int wid = blockIdx.x * 4 + (threadIdx.x >> 6);
    int lane = threadIdx.x & 63;
    long v = (long)wid * 4 + (lane >> 4);
    int l = lane & 15;
    if (v >= NNODES) return;
    int start = row_ptr[v], cnt = counts[v];
    float a0=0.f,a1=0.f,a2=0.f,a3=0.f,a4=0.f,a5=0.f,a6=0.f,a7=0.f;
    float b0=0.f,b1=0.f,b2=0.f,b3=0.f,b4=0.f,b5=0.f,b6=0.f,b7=0.f;
    const uint4* Mu = (const uint4*)M;
    int e = 0;
    for (; e + 3 < cnt; e += 4) {
        int s0 = es[start + e],     s1 = es[start + e + 1];
        int s2 = es[start + e + 2], s3 = es[start + e + 3];
        uint4 u0 = Mu[(long)s0 * 16 + l];
        uint4 u1 = Mu[(long)s1 * 16 + l];
        uint4 u2 = Mu[(long)s2 * 16 + l];
        uint4 u3 = Mu[(long)s3 * 16 + l];
        a0 += bfu((u16)u0.x); a1 += bfu((u16)(u0.x >> 16));
        a2 += bfu((u16)u0.y); a3 += bfu((u16)(u0.y >> 16));
        a4 += bfu((u16)u0.z); a5 += bfu((u16)(u0.z >> 16));
        a6 += bfu((u16)u0.w); a7 += bfu((u16)(u0.w >> 16));
        b0 += bfu((u16)u1.x); b1 += bfu((u16)(u1.x >> 16));
        b2 += bfu((u16)u1.y); b3 += bfu((u16)(u1.y >> 16));
        b4 += bfu((u16)u1.z); b5 += bfu((u16)(u1.z >> 16));
        b6 += bfu((u16)u1.w); b7 += bfu((u16)(u1.w >> 16));
        a0 += bfu((u16)u2.x); a1 += bfu((u16)(u2.x >> 16));
        a2 += bfu((u16)u2.y); a3 += bfu((u16)(u2.y >> 16));
        a4 += bfu((u16)u2.z); a5 += bfu((u16)(u2.z >> 16));
        a6 += bfu((u16)u2.w); a7 += bfu((u16)(u2.w >> 16));
        b0 += bfu((u16)u3.x); b1 += bfu((u16)(u3.x >> 16));
        b2 += bfu((u16)u3.y); b3 += bfu((u16)(u3.y >> 16));
        b4 += bfu((u16)u3.z); b5 += bfu((u16)(u3.z >> 16));
        b6 += bfu((u16)u3.w); b7 += bfu((u16)(u3.w >> 16));
    }
    for (; e < cnt; e++) {
        int s0 = es[start + e];
        uint4 u0 = Mu[(long)s0 * 16 + l];
        a0 += bfu((u16)u0.x); a1 += bfu((u16)(u0.x >> 16));
        a2 += bfu((u16)u0.y); a3 += bfu((u16)(u0.y >> 16));
        a4 += bfu((u16)u0.z); a5 += bfu((u16)(u0.z >> 16));
        a6 += bfu((u16)u0.w); a7 += bfu((u16)(u0.w >> 16));
    }
    a0 += b0; a1 += b1; a2 += b2; a3 += b3;
    a4 += b4; a5 += b5; a6 += b6; a7 += b7;
    uint4* xu = (uint4*)x;
    uint4 xv = xu[v * 16 + l];
    xv.x = pack2(bfu((u16)xv.x) + sp_f(a0), bfu((u16)(xv.x >> 16)) + sp_f(a1));
    xv.y = pack2(bfu((u16)xv.y) + sp_f(a2), bfu((u16)(xv.y >> 16)) + sp_f(a3));
    xv.z = pack2(bfu((u16)xv.z) + sp_f(a4), bfu((u16)(xv.z >> 16)) + sp_f(a5));
    xv.w = pack2(bfu((u16)xv.w) + sp_f(a6), bfu((u16)(xv.w >> 16)) + sp_f(a7));
    xu[v * 16 + l] = xv;
}

// ---------------- pooling: xsum[g] = sum of x rows of graph g (atomic flush) ----------------
__global__ __launch_bounds__(256) void pool_kernel(const u16* __restrict__ x,
                                                   const int* __restrict__ gidx,
                                                   float* __restrict__ xsum){
    int wave = blockIdx.x * 4 + (threadIdx.x >> 6);
    int lane = threadIdx.x & 63;
    long base = (long)wave * 64;
    if (base >= NNODES) return;
    long end = base + 64; if (end > NNODES) end = NNODES;
    const unsigned* xu = (const unsigned*)x;
    int gcur = gidx[base];
    float a0 = 0.f, a1 = 0.f;
    for (long v = base; v < end; v++) {
        int g = gidx[v];                           // wave-uniform
        if (g != gcur) {
            atomicAdd(&xsum[gcur * HF + lane * 2 + 0], a0);
            atomicAdd(&xsum[gcur * HF + lane * 2 + 1], a1);
            a0 = a1 = 0.f; gcur = g;
        }
        unsigned u = xu[v * 64 + lane];
        a0 += bfu((u16)u);
        a1 += bfu((u16)(u >> 16));
    }
    atomicAdd(&xsum[gcur * HF + lane * 2 + 0], a0);
    atomicAdd(&xsum[gcur * HF + lane * 2 + 1], a1);
}

// ---------------- head via transposed 16x16 MFMA, bf16 hi+lo activations ----------------
__global__ __launch_bounds__(256) void head_mfma(const float* __restrict__ xsum,
                                                 const void* __restrict__ ncnt,
                                                 const u16* __restrict__ pwp,
                                                 const u16* __restrict__ pf1,
                                                 const u16* __restrict__ pf2,
                                                 const void* __restrict__ bfc1,
                                                 const void* __restrict__ bfc2,
                                                 const void* __restrict__ Wr,
                                                 const void* __restrict__ br,
                                                 void* __restrict__ out,
                                                 const void* __restrict__ probe){
    __shared__ u16 hibuf[2][GB][136];
    __shared__ u16 lobuf[2][GB][136];
    const int t = threadIdx.x;
    const int w = t >> 6, lane = t & 63;
    const int quad = lane >> 4, nr = lane & 15;
    const bool f32 = is_f32(probe);
    const int g0 = blockIdx.x * GB;

    for (int i = t; i < GB * 64; i += 256) {
        int g = i >> 6, c = (i & 63) * 2;
        float f0 = xsum[(g0 + g) * HF + c], f1 = xsum[(g0 + g) * HF + c + 1];
        u16 h0 = f2bf(f0), h1 = f2bf(f1);
        *(unsigned*)&hibuf[0][g][c] = (unsigned)h0 | ((unsigned)h1 << 16);
        *(unsigned*)&lobuf[0][g][c] = pack2(f0 - bfu(h0), f1 - bfu(h1));
    }
    __syncthreads();

    float rc[2];
#pragma unroll
    for (int nt = 0; nt < 2; nt++) rc[nt] = RCP1(lf(ncnt, g0 + nt * 16 + nr, f32));

    int cur = 0;
    for (int layer = 0; layer < 3; layer++) {
        const u16* pw = (layer == 0) ? pwp : (layer == 1) ? pf1 : pf2;
        const void* bias = (layer == 1) ? bfc1 : bfc2;
        int nxt = cur ^ 1;
#pragma unroll
        for (int c = 0; c < 2; c++) {
            int et = w * 2 + c;
            short8 A[4];
#pragma unroll
            for (int kt = 0; kt < 4; kt++)
                A[kt] = *(const short8*)(pw + (((kt * 8 + et) * 64 + lane) << 3));
#pragma unroll
            for (int nt = 0; nt < 2; nt++) {
                f32x4 acc = {0.f, 0.f, 0.f, 0.f};
#pragma unroll
                for (int kt = 0; kt < 4; kt++) {
                    short8 bh = *(const short8*)(&hibuf[cur][nt * 16 + nr][kt * 32 + quad * 8]);
                    short8 bl = *(const short8*)(&lobuf[cur][nt * 16 + nr][kt * 32 + quad * 8]);
                    acc = __builtin_amdgcn_mfma_f32_16x16x32_bf16(A[kt], bh, acc, 0, 0, 0);
                    acc = __builtin_amdgcn_mfma_f32_16x16x32_bf16(A[kt], bl, acc, 0, 0, 0);
                }
                int feat0 = et * 16 + quad * 4;
                float f[4];
#pragma unroll
                for (int r = 0; r < 4; r++) {
                    float a = (layer == 0) ? acc[r] * rc[nt]
                                           : acc[r] + lf(bias, feat0 + r, f32);
                    f[r] = sp_f(a);
                }
                u16 h[4]; float lo[4];
#pragma unroll
                for (int r = 0; r < 4; r++) { h[r] = f2bf(f[r]); lo[r] = f[r] - bfu(h[r]); }
                uint2 dh, dl;
                dh.x = (unsigned)h[0] | ((unsigned)h[1] << 16);
                dh.y = (unsigned)h[2] | ((unsigned)h[3] << 16);
                dl.x = pack2(lo[0], lo[1]);
                dl.y = pack2(lo[2], lo[3]);
                *(uint2*)&hibuf[nxt][nt * 16 + nr][feat0] = dh;
                *(uint2*)&lobuf[nxt][nt * 16 + nr][feat0] = dl;
            }
        }
        __syncthreads();
        cur = nxt;
    }

    int g = t >> 3, sub = t & 7;
    float p = 0.f;
    for (int k = sub * 16; k < sub * 16 + 16; k++) {
        float v = bfu(hibuf[cur][g][k]) + bfu(lobuf[cur][g][k]);
        p += v * lf(Wr, k, f32);
    }
    p += __shfl_down(p, 4, 64);
    p += __shfl_down(p, 2, 64);
    p += __shfl_down(p, 1, 64);
    if (sub == 0) {
        float res = p + lf(br, 0, f32);
        if (f32) ((float*)out)[g0 + g] = res;
        else     ((u16*)out)[g0 + g]  = f2bf(res);
    }
}

extern "C" void kernel_launch(void* const* d_in, const int* in_sizes, int n_in,
                              void* d_out, int out_size, void* d_ws, size_t ws_size,
                              hipStream_t stream) {
    const int* nodes = (const int*)d_in[0];
    const int* esrc  = (const int*)d_in[1];
    const int* etgt  = (const int*)d_in[2];
    const int* gidx  = (const int*)d_in[3];

    size_t off = 0;
    char* w = (char*)d_ws;
    auto take = [&](size_t bytes) -> void* {
        void* p = w + off;
        off = (off + bytes + 255) & ~(size_t)255;
        return p;
    };

    u16* pwg     = (u16*)take((size_t)3 * HF * HF * 2);
    u16* pwe1    = (u16*)take((size_t)3 * HF * EF * 2);
    u16* pwe2    = (u16*)take((size_t)3 * EF * HF * 2);
    u16* pwp     = (u16*)take((size_t)HF * HF * 2);
    u16* pf1     = (u16*)take((size_t)HF * HF * 2);
    u16* pf2     = (u16*)take((size_t)HF * HF * 2);
    int* counts  = (int*)take((size_t)NNODES * 4);
    int* row_ptr = (int*)take((size_t)NNODES * 4);
    int* cursor  = (int*)take((size_t)NNODES * 4);
    int* es      = (int*)take((size_t)NEDGES * 4);
    int* bsums   = (int*)take(2048);
    int* boffs   = (int*)take(2048);
    float* xsum  = (float*)take((size_t)NGRAPHS * HF * 4);
    u16* x       = (u16*)take((size_t)NNODES * HF * 2);
    u16* M       = (u16*)take((size_t)NNODES * HF * 2);

    hipMemsetAsync(counts, 0, (size_t)NNODES * 4, stream);

    // prep: conv repack (960) + head repack (192) + count (2344) + xsum zero (64)
    prep_kernel<<<3560, 256, 0, stream>>>(d_in[6], d_in[7], d_in[8],
                                          d_in[9], d_in[10], d_in[12],
                                          pwg, pwe1, pwe2, pwp, pf1, pf2,
                                          d_in[5], etgt, counts, xsum);

    const int NB_SCAN = (NNODES + 255) / 256;      // 391
    const int NB_EDGE = (NEDGES + 255) / 256;      // 2344
    scan1_kernel<<<NB_SCAN, 256, 0, stream>>>(counts, row_ptr, bsums);
    scan2_kernel<<<1, 512, 0, stream>>>(bsums, boffs, NB_SCAN);
    scan3_kernel<<<NB_SCAN, 256, 0, stream>>>(row_ptr, boffs, cursor);
    fill_kernel<<<NB_EDGE, 256, 0, stream>>>(esrc, etgt, cursor, es);

    const int NBA = (NNODES + 15) / 16;            // 6250
    conv0_mfma<<<GRID_CONV, 256, 0, stream>>>(nodes, d_in[5], x, pwg, pwe1, pwe2, M);
    agg_kernel<<<NBA, 256, 0, stream>>>(M, row_ptr, counts, es, x);
    conv_mfma<<<GRID_CONV, 256, 0, stream>>>(x,
        pwg + (size_t)1 * HF * HF, pwe1 + (size_t)1 * HF * EF, pwe2 + (size_t)1 * EF * HF, M);
    agg_kernel<<<NBA, 256, 0, stream>>>(M, row_ptr, counts, es, x);
    conv_mfma<<<GRID_CONV, 256, 0, stream>>>(x,
        pwg + (size_t)2 * HF * HF, pwe1 + (size_t)2 * HF * EF, pwe2 + (size_t)2 * EF * HF, M);
    agg_kernel<<<NBA, 256, 0, stream>>>(M, row_ptr, counts, es, x);

    pool_kernel<<<(NNODES + 255) / 256, 256, 0, stream>>>(x, gidx, xsum);
    head_mfma<<<NGRAPHS / GB, 256, 0, stream>>>(xsum, d_in[4], pwp, pf1, pf2,
                                                d_in[11], d_in[13], d_in[14], d_in[15],
                                                d_out, d_in[5]);
}